// Round 1
// baseline (1258.768 us; speedup 1.0000x reference)
//
#include <hip/hip_runtime.h>
#include <math.h>

#define NN 100000
#define EE 1600000
#define IND 256
#define NB 391          // ceil(NN/256)
#define SLOPE 0.2f

// ---------------------------------------------------------------------------
// V matrices: alpha = h @ V,  V[et][k][h] = sum_c W[et][k][h*8+c] * a[et][h][c]
// ---------------------------------------------------------------------------
__global__ __launch_bounds__(512) void prep_V(
    const float* __restrict__ Ws, const float* __restrict__ as_,
    const float* __restrict__ Wd, const float* __restrict__ ad_,
    float* __restrict__ Vs, float* __restrict__ Vd) {
  int t = threadIdx.x;             // 0..511
  int half = t >> 8;
  int r = t & 255;
  int et = r >> 6, k = (r >> 3) & 7, hh = r & 7;
  const float* W = half ? Wd : Ws;
  const float* a = half ? ad_ : as_;
  float acc = 0.f;
#pragma unroll
  for (int c = 0; c < 8; ++c)
    acc += W[et * 512 + k * 64 + hh * 8 + c] * a[et * 64 + hh * 8 + c];
  (half ? Vd : Vs)[et * 64 + k * 8 + hh] = acc;
}

// ---------------------------------------------------------------------------
// FC: h[type][n][0..7] = x[n] @ Wfc + b.  One wave per row (coalesced 1KB/row).
// ---------------------------------------------------------------------------
__global__ __launch_bounds__(256) void fc_kernel(
    const float* __restrict__ xa, const float* __restrict__ xp,
    const float* __restrict__ Wa, const float* __restrict__ ba,
    const float* __restrict__ Wp, const float* __restrict__ bp,
    float* __restrict__ h) {
  int wid = (blockIdx.x * blockDim.x + threadIdx.x) >> 6;
  int lane = threadIdx.x & 63;
  if (wid >= 2 * NN) return;
  int type = wid >= NN;
  int row = type ? wid - NN : wid;
  const float* x = (type ? xp : xa) + (size_t)row * IND;
  const float* W = type ? Wp : Wa;
  const float* b = type ? bp : ba;
  float4 xv = *(const float4*)(x + lane * 4);
  float xs_[4] = {xv.x, xv.y, xv.z, xv.w};
  float acc[8];
#pragma unroll
  for (int c = 0; c < 8; ++c) acc[c] = 0.f;
#pragma unroll
  for (int j = 0; j < 4; ++j) {
    int k = lane * 4 + j;
    float xk = xs_[j];
#pragma unroll
    for (int c = 0; c < 8; ++c) acc[c] = fmaf(xk, W[k * 8 + c], acc[c]);
  }
#pragma unroll
  for (int c = 0; c < 8; ++c) {
#pragma unroll
    for (int off = 32; off; off >>= 1) acc[c] += __shfl_xor(acc[c], off, 64);
  }
  if (lane < 8) {
    float v = acc[0];
#pragma unroll
    for (int c = 1; c < 8; ++c)
      if (lane == c) v = acc[c];
    h[((size_t)type * NN + row) * 8 + lane] = v + b[lane];
  }
}

// ---------------------------------------------------------------------------
// alpha_s[et][n][h] = h[n] @ Vs[et]   (only src-side alphas are materialized)
// ---------------------------------------------------------------------------
__global__ __launch_bounds__(256) void node_alpha(
    const float* __restrict__ h, const float* __restrict__ Vs,
    float* __restrict__ alpha_s) {
  int n = blockIdx.x * 256 + threadIdx.x;
  if (n >= 2 * NN) return;
  int type = n >= NN;
  int nn = type ? n - NN : n;
  float4 h0 = *(const float4*)(h + (size_t)n * 8);
  float4 h1 = *(const float4*)(h + (size_t)n * 8 + 4);
  float hv[8] = {h0.x, h0.y, h0.z, h0.w, h1.x, h1.y, h1.z, h1.w};
#pragma unroll
  for (int which = 0; which < 2; ++which) {
    int et = type + 2 * which;  // a: 0,2   p: 1,3
    float o[8];
#pragma unroll
    for (int hh = 0; hh < 8; ++hh) {
      float acc = 0.f;
#pragma unroll
      for (int k = 0; k < 8; ++k)
        acc = fmaf(hv[k], Vs[et * 64 + k * 8 + hh], acc);
      o[hh] = acc;
    }
    float* dst = alpha_s + ((size_t)et * NN + nn) * 8;
    *(float4*)dst = make_float4(o[0], o[1], o[2], o[3]);
    *(float4*)(dst + 4) = make_float4(o[4], o[5], o[6], o[7]);
  }
}

// ---------------------------------------------------------------------------
// CSR build: histogram -> two-level exclusive scan -> scatter
// ---------------------------------------------------------------------------
__global__ __launch_bounds__(256) void hist_kernel(
    const int* __restrict__ e0, const int* __restrict__ e1,
    const int* __restrict__ e2, const int* __restrict__ e3,
    int* __restrict__ counts) {
  int e = blockIdx.x * 256 + threadIdx.x;
  if (e >= EE) return;
  int et = blockIdx.y;
  const int* ei = et == 0 ? e0 : et == 1 ? e1 : et == 2 ? e2 : e3;
  int d = ei[EE + e];
  atomicAdd(&counts[(size_t)et * NN + d], 1);
}

__global__ __launch_bounds__(256) void scan1_kernel(
    const int* __restrict__ counts, int* __restrict__ rowptr,
    int* __restrict__ partials) {
  __shared__ int s[256];
  int et = blockIdx.y;
  int gid = blockIdx.x * 256 + threadIdx.x;
  int v = (gid < NN) ? counts[(size_t)et * NN + gid] : 0;
  s[threadIdx.x] = v;
  __syncthreads();
#pragma unroll
  for (int off = 1; off < 256; off <<= 1) {
    int t = (threadIdx.x >= off) ? s[threadIdx.x - off] : 0;
    __syncthreads();
    s[threadIdx.x] += t;
    __syncthreads();
  }
  if (gid < NN) rowptr[(size_t)et * NN + gid] = s[threadIdx.x] - v;  // exclusive
  if (threadIdx.x == 255) partials[et * 512 + blockIdx.x] = s[255];
}

__global__ __launch_bounds__(512) void scan2_kernel(int* __restrict__ partials) {
  __shared__ int s[512];
  int et = blockIdx.x;
  int t = threadIdx.x;
  int v = (t < NB) ? partials[et * 512 + t] : 0;
  s[t] = v;
  __syncthreads();
#pragma unroll
  for (int off = 1; off < 512; off <<= 1) {
    int tv = (t >= off) ? s[t - off] : 0;
    __syncthreads();
    s[t] += tv;
    __syncthreads();
  }
  if (t < NB) partials[et * 512 + t] = s[t] - v;  // exclusive
}

__global__ __launch_bounds__(256) void fixup_kernel(
    int* __restrict__ rowptr, const int* __restrict__ partials) {
  int et = blockIdx.y;
  int gid = blockIdx.x * 256 + threadIdx.x;
  if (gid < NN) rowptr[(size_t)et * NN + gid] += partials[et * 512 + blockIdx.x];
}

__global__ __launch_bounds__(256) void scatter_kernel(
    const int* __restrict__ e0, const int* __restrict__ e1,
    const int* __restrict__ e2, const int* __restrict__ e3,
    const int* __restrict__ rowptr, int* __restrict__ cursor,
    int* __restrict__ edge_src) {
  int e = blockIdx.x * 256 + threadIdx.x;
  if (e >= EE) return;
  int et = blockIdx.y;
  const int* ei = et == 0 ? e0 : et == 1 ? e1 : et == 2 ? e2 : e3;
  int sidx = ei[e];
  int d = ei[EE + e];
  int pos = atomicAdd(&cursor[(size_t)et * NN + d], 1);
  edge_src[(size_t)et * EE + rowptr[(size_t)et * NN + d] + pos] = sidx;
}

// ---------------------------------------------------------------------------
// GAT pull: one thread per dst node. Accumulate g[h][k] = sum_e w_e[h]*h_src[k]
// and z[h]; project through Wsrc once per node at the end. No atomics.
// Softmax computed unshifted (shift-invariant; |e| <= ~8 so exp is safe).
// ---------------------------------------------------------------------------
__global__ __launch_bounds__(256) void gat_pull(
    const float* __restrict__ h, const float* __restrict__ alpha_s,
    const int* __restrict__ rowptr, const int* __restrict__ counts,
    const int* __restrict__ edge_src,
    const float* __restrict__ Wsrc_all, const float* __restrict__ Vd,
    const float* __restrict__ bias_all, float* __restrict__ out_et) {
  int n = blockIdx.x * 256 + threadIdx.x;
  if (n >= NN) return;
  int et = blockIdx.y;
  int st = et & 1;                           // src type: 0=a,1=p
  int dt = (et & 1) ^ (et < 2 ? 1 : 0);      // dst type
  const float* hsrc = h + (size_t)st * NN * 8;
  const float* hdst = h + (size_t)dt * NN * 8;
  const float* asrc = alpha_s + (size_t)et * NN * 8;
  const float* Ws = Wsrc_all + et * 512;
  const float* Vde = Vd + et * 64;
  const float* bs = bias_all + et * 64;

  float4 hd0 = *(const float4*)(hdst + (size_t)n * 8);
  float4 hd1 = *(const float4*)(hdst + (size_t)n * 8 + 4);
  float hd[8] = {hd0.x, hd0.y, hd0.z, hd0.w, hd1.x, hd1.y, hd1.z, hd1.w};
  float ad[8];
#pragma unroll
  for (int hh = 0; hh < 8; ++hh) {
    float acc = 0.f;
#pragma unroll
    for (int k = 0; k < 8; ++k) acc = fmaf(hd[k], Vde[k * 8 + hh], acc);
    ad[hh] = acc;
  }
  float g[64];
  float z[8];
#pragma unroll
  for (int i = 0; i < 64; ++i) g[i] = 0.f;
#pragma unroll
  for (int hh = 0; hh < 8; ++hh) z[hh] = 0.f;

  int start = rowptr[(size_t)et * NN + n];
  int deg = counts[(size_t)et * NN + n];
  const int* es = edge_src + (size_t)et * EE + start;
  for (int i = 0; i < deg; ++i) {
    int s = es[i];
    float4 a0 = *(const float4*)(hsrc + (size_t)s * 8);
    float4 a1 = *(const float4*)(hsrc + (size_t)s * 8 + 4);
    float4 b0 = *(const float4*)(asrc + (size_t)s * 8);
    float4 b1 = *(const float4*)(asrc + (size_t)s * 8 + 4);
    float hs[8] = {a0.x, a0.y, a0.z, a0.w, a1.x, a1.y, a1.z, a1.w};
    float as_[8] = {b0.x, b0.y, b0.z, b0.w, b1.x, b1.y, b1.z, b1.w};
#pragma unroll
    for (int hh = 0; hh < 8; ++hh) {
      float e = as_[hh] + ad[hh];
      e = e > 0.f ? e : SLOPE * e;
      float w = __expf(e);
      z[hh] += w;
#pragma unroll
      for (int k = 0; k < 8; ++k) g[hh * 8 + k] = fmaf(w, hs[k], g[hh * 8 + k]);
    }
  }

  float* op = out_et + ((size_t)et * NN + n) * 64;
#pragma unroll
  for (int hh = 0; hh < 8; ++hh) {
    float rz = 1.f / (z[hh] + 1e-16f);
    float o[8];
#pragma unroll
    for (int c = 0; c < 8; ++c) {
      float acc = 0.f;
#pragma unroll
      for (int k = 0; k < 8; ++k)
        acc = fmaf(g[hh * 8 + k], Ws[k * 64 + hh * 8 + c], acc);
      o[c] = acc * rz + bs[hh * 8 + c];
    }
    *(float4*)(op + hh * 8) = make_float4(o[0], o[1], o[2], o[3]);
    *(float4*)(op + hh * 8 + 4) = make_float4(o[4], o[5], o[6], o[7]);
  }
}

// ---------------------------------------------------------------------------
// Semantic attention keys: key[et] = sum_n tanh(out_et[n] @ Wk + bk)
// One wave per block; each lane owns a node row staged in its own LDS column
// (so the k-loop can be a runtime loop without spilling to scratch).
// ---------------------------------------------------------------------------
__global__ __launch_bounds__(64) void semantic_key(
    const float* __restrict__ out_et, const float* __restrict__ Wk,
    const float* __restrict__ bk, float* __restrict__ key) {
  __shared__ float srow[64 * 64];  // srow[k*64 + lane]
  int m = blockIdx.y;
  int lane = threadIdx.x;
  const float* base = out_et + (size_t)m * NN * 64;
  float ka[64];
#pragma unroll
  for (int j = 0; j < 64; ++j) ka[j] = 0.f;

  for (int n = blockIdx.x * 64 + lane; n < NN; n += gridDim.x * 64) {
    const float* row = base + (size_t)n * 64;
#pragma unroll
    for (int k4 = 0; k4 < 16; ++k4) {
      float4 v = ((const float4*)row)[k4];
      srow[(k4 * 4 + 0) * 64 + lane] = v.x;
      srow[(k4 * 4 + 1) * 64 + lane] = v.y;
      srow[(k4 * 4 + 2) * 64 + lane] = v.z;
      srow[(k4 * 4 + 3) * 64 + lane] = v.w;
    }
    float acc[64];
#pragma unroll
    for (int j = 0; j < 64; ++j) acc[j] = 0.f;
    for (int k = 0; k < 64; ++k) {        // runtime loop; Wk row -> s_loads
      float rk = srow[k * 64 + lane];
#pragma unroll
      for (int j = 0; j < 64; ++j) acc[j] = fmaf(rk, Wk[k * 64 + j], acc[j]);
    }
#pragma unroll
    for (int j = 0; j < 64; ++j) {
      float x = acc[j] + bk[j];
      float t = 1.f - 2.f / (__expf(2.f * x) + 1.f);  // tanh
      ka[j] += t;
    }
  }
#pragma unroll
  for (int j = 0; j < 64; ++j) {
#pragma unroll
    for (int off = 32; off; off >>= 1) ka[j] += __shfl_xor(ka[j], off, 64);
  }
  if (lane == 0) {
#pragma unroll
    for (int j = 0; j < 64; ++j) atomicAdd(&key[m * 64 + j], ka[j]);
  }
}

// ---------------------------------------------------------------------------
// Scores: softmax over each node-type's pair of edge types.
// Pairs: author = (et1, et2), paper = (et0, et3).
// ---------------------------------------------------------------------------
__global__ __launch_bounds__(64) void scores_k(
    const float* __restrict__ key, const float* __restrict__ q,
    float* __restrict__ wsc) {
  int l = threadIdx.x;
  float qv = q[l];
  float d[4];
#pragma unroll
  for (int m = 0; m < 4; ++m) {
    float p = qv * key[m * 64 + l];
#pragma unroll
    for (int off = 32; off; off >>= 1) p += __shfl_xor(p, off, 64);
    d[m] = p * (1.0f / NN);  // mean over nodes
  }
  if (l == 0) {
    {
      float mx = fmaxf(d[1], d[2]);
      float e1 = __expf(d[1] - mx), e2 = __expf(d[2] - mx);
      float inv = 1.f / (e1 + e2);
      wsc[1] = e1 * inv;
      wsc[2] = e2 * inv;
    }
    {
      float mx = fmaxf(d[0], d[3]);
      float e0 = __expf(d[0] - mx), e3 = __expf(d[3] - mx);
      float inv = 1.f / (e0 + e3);
      wsc[0] = e0 * inv;
      wsc[3] = e3 * inv;
    }
  }
}

__global__ __launch_bounds__(256) void combine_kernel(
    const float* __restrict__ out_et, const float* __restrict__ wsc,
    float* __restrict__ out) {
  size_t i4 = (size_t)blockIdx.x * 256 + threadIdx.x;  // float4 index over [2][N][16]
  if (i4 >= (size_t)2 * NN * 16) return;
  int type = i4 >= (size_t)NN * 16;
  size_t r4 = type ? i4 - (size_t)NN * 16 : i4;
  int m0 = type ? 0 : 1;
  int m1 = type ? 3 : 2;
  float s0 = wsc[m0], s1 = wsc[m1];
  float4 a = ((const float4*)out_et)[(size_t)m0 * NN * 16 + r4];
  float4 b = ((const float4*)out_et)[(size_t)m1 * NN * 16 + r4];
  float4 o;
  o.x = s0 * a.x + s1 * b.x;
  o.y = s0 * a.y + s1 * b.y;
  o.z = s0 * a.z + s1 * b.z;
  o.w = s0 * a.w + s1 * b.w;
  ((float4*)out)[i4] = o;
}

// ---------------------------------------------------------------------------
extern "C" void kernel_launch(void* const* d_in, const int* in_sizes, int n_in,
                              void* d_out, int out_size, void* d_ws,
                              size_t ws_size, hipStream_t stream) {
  const float* x_a = (const float*)d_in[0];
  const float* x_p = (const float*)d_in[1];
  const int* ei0 = (const int*)d_in[2];   // a->p
  const int* ei1 = (const int*)d_in[3];   // p->a
  const int* ei2 = (const int*)d_in[4];   // a->a
  const int* ei3 = (const int*)d_in[5];   // p->p
  const float* Wfa = (const float*)d_in[6];
  const float* bfa = (const float*)d_in[7];
  const float* Wfp = (const float*)d_in[8];
  const float* bfp = (const float*)d_in[9];
  const float* gWs = (const float*)d_in[10];
  const float* gWd = (const float*)d_in[11];
  const float* gas = (const float*)d_in[12];
  const float* gad = (const float*)d_in[13];
  const float* gb = (const float*)d_in[14];
  const float* Wk = (const float*)d_in[15];
  const float* bk = (const float*)d_in[16];
  const float* q = (const float*)d_in[17];
  float* out = (float*)d_out;
  (void)in_sizes; (void)n_in; (void)out_size; (void)ws_size;

  float* ws = (float*)d_ws;
  float* h = ws;                                     // 2*N*8
  float* alpha_s = h + (size_t)2 * NN * 8;           // 4*N*8
  float* out_et = alpha_s + (size_t)4 * NN * 8;      // 4*N*64
  float* Vs = out_et + (size_t)4 * NN * 64;          // 256
  float* Vd = Vs + 256;                              // 256
  float* key = Vd + 256;                             // 256
  float* wsc = key + 256;                            // 8 (4 used)
  int* counts = (int*)(wsc + 8);                     // 4*N
  int* rowptr = counts + (size_t)4 * NN;             // 4*N
  int* cursor = rowptr + (size_t)4 * NN;             // 4*N
  int* partials = cursor + (size_t)4 * NN;           // 4*512
  int* edge_src = partials + 4 * 512;                // 4*E

  hipMemsetAsync(counts, 0, (size_t)12 * NN * sizeof(int), stream);  // counts+rowptr+cursor
  hipMemsetAsync(key, 0, 256 * sizeof(float), stream);

  prep_V<<<1, 512, 0, stream>>>(gWs, gas, gWd, gad, Vs, Vd);
  fc_kernel<<<50000, 256, 0, stream>>>(x_a, x_p, Wfa, bfa, Wfp, bfp, h);
  node_alpha<<<(2 * NN + 255) / 256, 256, 0, stream>>>(h, Vs, alpha_s);
  hist_kernel<<<dim3((EE + 255) / 256, 4), 256, 0, stream>>>(ei0, ei1, ei2, ei3, counts);
  scan1_kernel<<<dim3(NB, 4), 256, 0, stream>>>(counts, rowptr, partials);
  scan2_kernel<<<4, 512, 0, stream>>>(partials);
  fixup_kernel<<<dim3(NB, 4), 256, 0, stream>>>(rowptr, partials);
  scatter_kernel<<<dim3((EE + 255) / 256, 4), 256, 0, stream>>>(ei0, ei1, ei2, ei3,
                                                                rowptr, cursor, edge_src);
  gat_pull<<<dim3(NB, 4), 256, 0, stream>>>(h, alpha_s, rowptr, counts, edge_src,
                                            gWs, Vd, gb, out_et);
  semantic_key<<<dim3(256, 4), 64, 0, stream>>>(out_et, Wk, bk, key);
  scores_k<<<1, 64, 0, stream>>>(key, q, wsc);
  combine_kernel<<<(2 * NN * 16 + 255) / 256, 256, 0, stream>>>(out_et, wsc, out);
}

// Round 2
// 800.254 us; speedup vs baseline: 1.5730x; 1.5730x over previous
//
#include <hip/hip_runtime.h>
#include <math.h>

#define NN 100000
#define EE 1600000
#define IND 256
#define SLOPE 0.2f

#define BUKBITS 9
#define BUKSZ 512            // nodes per bucket
#define NBUK 196             // ceil(NN/512)
#define CAP 8960             // bucket capacity: mean 8192 + 8*sigma(90), mult of 256
#define CHUNK 4096           // edges per bin block
#define BINBLK 391           // ceil(EE/CHUNK)

// ---------------------------------------------------------------------------
// V matrices: alpha = h @ V,  V[et][k][h] = sum_c W[et][k][h*8+c] * a[et][h][c]
// ---------------------------------------------------------------------------
__global__ __launch_bounds__(512) void prep_V(
    const float* __restrict__ Ws, const float* __restrict__ as_,
    const float* __restrict__ Wd, const float* __restrict__ ad_,
    float* __restrict__ Vs, float* __restrict__ Vd) {
  int t = threadIdx.x;             // 0..511
  int half = t >> 8;
  int r = t & 255;
  int et = r >> 6, k = (r >> 3) & 7, hh = r & 7;
  const float* W = half ? Wd : Ws;
  const float* a = half ? ad_ : as_;
  float acc = 0.f;
#pragma unroll
  for (int c = 0; c < 8; ++c)
    acc += W[et * 512 + k * 64 + hh * 8 + c] * a[et * 64 + hh * 8 + c];
  (half ? Vd : Vs)[et * 64 + k * 8 + hh] = acc;
}

// ---------------------------------------------------------------------------
// FC: h[type][n][0..7] = x[n] @ Wfc + b.  One wave per row (coalesced 1KB/row).
// ---------------------------------------------------------------------------
__global__ __launch_bounds__(256) void fc_kernel(
    const float* __restrict__ xa, const float* __restrict__ xp,
    const float* __restrict__ Wa, const float* __restrict__ ba,
    const float* __restrict__ Wp, const float* __restrict__ bp,
    float* __restrict__ h) {
  int wid = (blockIdx.x * blockDim.x + threadIdx.x) >> 6;
  int lane = threadIdx.x & 63;
  if (wid >= 2 * NN) return;
  int type = wid >= NN;
  int row = type ? wid - NN : wid;
  const float* x = (type ? xp : xa) + (size_t)row * IND;
  const float* W = type ? Wp : Wa;
  const float* b = type ? bp : ba;
  float4 xv = *(const float4*)(x + lane * 4);
  float xs_[4] = {xv.x, xv.y, xv.z, xv.w};
  float acc[8];
#pragma unroll
  for (int c = 0; c < 8; ++c) acc[c] = 0.f;
#pragma unroll
  for (int j = 0; j < 4; ++j) {
    int k = lane * 4 + j;
    float xk = xs_[j];
#pragma unroll
    for (int c = 0; c < 8; ++c) acc[c] = fmaf(xk, W[k * 8 + c], acc[c]);
  }
#pragma unroll
  for (int c = 0; c < 8; ++c) {
#pragma unroll
    for (int off = 32; off; off >>= 1) acc[c] += __shfl_xor(acc[c], off, 64);
  }
  if (lane < 8) {
    float v = acc[0];
#pragma unroll
    for (int c = 1; c < 8; ++c)
      if (lane == c) v = acc[c];
    h[((size_t)type * NN + row) * 8 + lane] = v + b[lane];
  }
}

// ---------------------------------------------------------------------------
// alpha_s[et][n][h] = h[n] @ Vs[et]
// ---------------------------------------------------------------------------
__global__ __launch_bounds__(256) void node_alpha(
    const float* __restrict__ h, const float* __restrict__ Vs,
    float* __restrict__ alpha_s) {
  int n = blockIdx.x * 256 + threadIdx.x;
  if (n >= 2 * NN) return;
  int type = n >= NN;
  int nn = type ? n - NN : n;
  float4 h0 = *(const float4*)(h + (size_t)n * 8);
  float4 h1 = *(const float4*)(h + (size_t)n * 8 + 4);
  float hv[8] = {h0.x, h0.y, h0.z, h0.w, h1.x, h1.y, h1.z, h1.w};
#pragma unroll
  for (int which = 0; which < 2; ++which) {
    int et = type + 2 * which;  // a: 0,2   p: 1,3
    float o[8];
#pragma unroll
    for (int hh = 0; hh < 8; ++hh) {
      float acc = 0.f;
#pragma unroll
      for (int k = 0; k < 8; ++k)
        acc = fmaf(hv[k], Vs[et * 64 + k * 8 + hh], acc);
      o[hh] = acc;
    }
    float* dst = alpha_s + ((size_t)et * NN + nn) * 8;
    *(float4*)dst = make_float4(o[0], o[1], o[2], o[3]);
    *(float4*)(dst + 4) = make_float4(o[4], o[5], o[6], o[7]);
  }
}

// ---------------------------------------------------------------------------
// Phase 1: bucket binning. Each block stages CHUNK edges in LDS, histograms
// into NBUK buckets (dst>>9), reserves space with ONE global atomic per
// (block,bucket), flushes dense ~170B chunks. Packed: src | (dst&511)<<17.
// ---------------------------------------------------------------------------
__global__ __launch_bounds__(256) void bin_kernel(
    const int* __restrict__ e0, const int* __restrict__ e1,
    const int* __restrict__ e2, const int* __restrict__ e3,
    int* __restrict__ gcur, int* __restrict__ edge_src) {
  __shared__ int s_pack[CHUNK];
  __shared__ unsigned char s_buk[CHUNK];
  __shared__ int s_hist[NBUK], s_base[NBUK], s_cur[NBUK];
  int et = blockIdx.y;
  const int* ei = et == 0 ? e0 : et == 1 ? e1 : et == 2 ? e2 : e3;
  int t = threadIdx.x;
  for (int b = t; b < NBUK; b += 256) { s_hist[b] = 0; s_cur[b] = 0; }
  __syncthreads();
  int base = blockIdx.x * CHUNK;
#pragma unroll
  for (int r = 0; r < CHUNK / 256; ++r) {
    int i = r * 256 + t;
    int e = base + i;
    int bk = 255;
    if (e < EE) {
      int s = ei[e];
      int d = ei[EE + e];
      s_pack[i] = s | ((d & (BUKSZ - 1)) << 17);
      bk = d >> BUKBITS;
      atomicAdd(&s_hist[bk], 1);
    }
    s_buk[i] = (unsigned char)bk;
  }
  __syncthreads();
  for (int b = t; b < NBUK; b += 256)
    s_base[b] = atomicAdd(&gcur[et * NBUK + b], s_hist[b]);
  __syncthreads();
#pragma unroll
  for (int r = 0; r < CHUNK / 256; ++r) {
    int i = r * 256 + t;
    int bk = s_buk[i];
    if (bk != 255) {
      int pos = s_base[bk] + atomicAdd(&s_cur[bk], 1);
      if (pos < CAP)  // statistically impossible overflow guard
        edge_src[(size_t)(et * NBUK + bk) * CAP + pos] = s_pack[i];
    }
  }
}

// ---------------------------------------------------------------------------
// Phase 2: per-bucket CSR. Stage whole bucket in LDS, hist over 512 local
// nodes, scan, write counts + absolute rowptr, scatter src in-place (dense).
// ---------------------------------------------------------------------------
__global__ __launch_bounds__(256) void csr_kernel(
    const int* __restrict__ gcur, int* __restrict__ edge_src,
    int* __restrict__ counts, int* __restrict__ rowptr) {
  __shared__ int s_data[CAP];
  __shared__ int s_hist[BUKSZ], s_off[BUKSZ], s_part[256];
  int buk = blockIdx.x, et = blockIdx.y, t = threadIdx.x;
  int bsz = gcur[et * NBUK + buk];
  if (bsz > CAP) bsz = CAP;
  int ebase = (et * NBUK + buk) * CAP;
  for (int j = t; j < BUKSZ; j += 256) s_hist[j] = 0;
  __syncthreads();
  for (int i = t; i < bsz; i += 256) {
    int v = edge_src[ebase + i];
    s_data[i] = v;
    atomicAdd(&s_hist[v >> 17], 1);
  }
  __syncthreads();
  int b2 = t * 2;
  int a0 = s_hist[b2], a1 = s_hist[b2 + 1];
  int tot = a0 + a1;
  s_part[t] = tot;
  __syncthreads();
#pragma unroll
  for (int off = 1; off < 256; off <<= 1) {
    int v = (t >= off) ? s_part[t - off] : 0;
    __syncthreads();
    s_part[t] += v;
    __syncthreads();
  }
  int ex = s_part[t] - tot;
  s_off[b2] = ex;
  s_off[b2 + 1] = ex + a0;
  __syncthreads();
  for (int j = t; j < BUKSZ; j += 256) {
    int node = buk * BUKSZ + j;
    if (node < NN) {
      counts[(size_t)et * NN + node] = s_hist[j];
      rowptr[(size_t)et * NN + node] = ebase + s_off[j];
    }
  }
  __syncthreads();
  for (int i = t; i < bsz; i += 256) {
    int v = s_data[i];
    int pos = atomicAdd(&s_off[v >> 17], 1);
    edge_src[ebase + pos] = v & 0x1FFFF;
  }
}

// ---------------------------------------------------------------------------
// GAT pull: one thread per dst node. Accumulate g[h][k] = sum_e w_e[h]*h_src[k]
// and z[h]; project through Wsrc once per node. rowptr is ABSOLUTE.
// ---------------------------------------------------------------------------
__global__ __launch_bounds__(256) void gat_pull(
    const float* __restrict__ h, const float* __restrict__ alpha_s,
    const int* __restrict__ rowptr, const int* __restrict__ counts,
    const int* __restrict__ edge_src,
    const float* __restrict__ Wsrc_all, const float* __restrict__ Vd,
    const float* __restrict__ bias_all, float* __restrict__ out_et) {
  int n = blockIdx.x * 256 + threadIdx.x;
  if (n >= NN) return;
  int et = blockIdx.y;
  int st = et & 1;                           // src type: 0=a,1=p
  int dt = (et & 1) ^ (et < 2 ? 1 : 0);      // dst type
  const float* hsrc = h + (size_t)st * NN * 8;
  const float* hdst = h + (size_t)dt * NN * 8;
  const float* asrc = alpha_s + (size_t)et * NN * 8;
  const float* Ws = Wsrc_all + et * 512;
  const float* Vde = Vd + et * 64;
  const float* bs = bias_all + et * 64;

  float4 hd0 = *(const float4*)(hdst + (size_t)n * 8);
  float4 hd1 = *(const float4*)(hdst + (size_t)n * 8 + 4);
  float hd[8] = {hd0.x, hd0.y, hd0.z, hd0.w, hd1.x, hd1.y, hd1.z, hd1.w};
  float ad[8];
#pragma unroll
  for (int hh = 0; hh < 8; ++hh) {
    float acc = 0.f;
#pragma unroll
    for (int k = 0; k < 8; ++k) acc = fmaf(hd[k], Vde[k * 8 + hh], acc);
    ad[hh] = acc;
  }
  float g[64];
  float z[8];
#pragma unroll
  for (int i = 0; i < 64; ++i) g[i] = 0.f;
#pragma unroll
  for (int hh = 0; hh < 8; ++hh) z[hh] = 0.f;

  int start = rowptr[(size_t)et * NN + n];
  int deg = counts[(size_t)et * NN + n];
  const int* es = edge_src + start;
  for (int i = 0; i < deg; ++i) {
    int s = es[i];
    float4 a0 = *(const float4*)(hsrc + (size_t)s * 8);
    float4 a1 = *(const float4*)(hsrc + (size_t)s * 8 + 4);
    float4 b0 = *(const float4*)(asrc + (size_t)s * 8);
    float4 b1 = *(const float4*)(asrc + (size_t)s * 8 + 4);
    float hs[8] = {a0.x, a0.y, a0.z, a0.w, a1.x, a1.y, a1.z, a1.w};
    float as_[8] = {b0.x, b0.y, b0.z, b0.w, b1.x, b1.y, b1.z, b1.w};
#pragma unroll
    for (int hh = 0; hh < 8; ++hh) {
      float e = as_[hh] + ad[hh];
      e = e > 0.f ? e : SLOPE * e;
      float w = __expf(e);
      z[hh] += w;
#pragma unroll
      for (int k = 0; k < 8; ++k) g[hh * 8 + k] = fmaf(w, hs[k], g[hh * 8 + k]);
    }
  }

  float* op = out_et + ((size_t)et * NN + n) * 64;
#pragma unroll
  for (int hh = 0; hh < 8; ++hh) {
    float rz = 1.f / (z[hh] + 1e-16f);
    float o[8];
#pragma unroll
    for (int c = 0; c < 8; ++c) {
      float acc = 0.f;
#pragma unroll
      for (int k = 0; k < 8; ++k)
        acc = fmaf(g[hh * 8 + k], Ws[k * 64 + hh * 8 + c], acc);
      o[c] = acc * rz + bs[hh * 8 + c];
    }
    *(float4*)(op + hh * 8) = make_float4(o[0], o[1], o[2], o[3]);
    *(float4*)(op + hh * 8 + 4) = make_float4(o[4], o[5], o[6], o[7]);
  }
}

// ---------------------------------------------------------------------------
// Semantic attention keys: key[et] = sum_n tanh(out_et[n] @ Wk + bk)
// ---------------------------------------------------------------------------
__global__ __launch_bounds__(64) void semantic_key(
    const float* __restrict__ out_et, const float* __restrict__ Wk,
    const float* __restrict__ bk, float* __restrict__ key) {
  __shared__ float srow[64 * 64];  // srow[k*64 + lane]
  int m = blockIdx.y;
  int lane = threadIdx.x;
  const float* base = out_et + (size_t)m * NN * 64;
  float ka[64];
#pragma unroll
  for (int j = 0; j < 64; ++j) ka[j] = 0.f;

  for (int n = blockIdx.x * 64 + lane; n < NN; n += gridDim.x * 64) {
    const float* row = base + (size_t)n * 64;
#pragma unroll
    for (int k4 = 0; k4 < 16; ++k4) {
      float4 v = ((const float4*)row)[k4];
      srow[(k4 * 4 + 0) * 64 + lane] = v.x;
      srow[(k4 * 4 + 1) * 64 + lane] = v.y;
      srow[(k4 * 4 + 2) * 64 + lane] = v.z;
      srow[(k4 * 4 + 3) * 64 + lane] = v.w;
    }
    float acc[64];
#pragma unroll
    for (int j = 0; j < 64; ++j) acc[j] = 0.f;
    for (int k = 0; k < 64; ++k) {
      float rk = srow[k * 64 + lane];
#pragma unroll
      for (int j = 0; j < 64; ++j) acc[j] = fmaf(rk, Wk[k * 64 + j], acc[j]);
    }
#pragma unroll
    for (int j = 0; j < 64; ++j) {
      float x = acc[j] + bk[j];
      float t = 1.f - 2.f / (__expf(2.f * x) + 1.f);  // tanh
      ka[j] += t;
    }
  }
#pragma unroll
  for (int j = 0; j < 64; ++j) {
#pragma unroll
    for (int off = 32; off; off >>= 1) ka[j] += __shfl_xor(ka[j], off, 64);
  }
  if (lane == 0) {
#pragma unroll
    for (int j = 0; j < 64; ++j) atomicAdd(&key[m * 64 + j], ka[j]);
  }
}

// ---------------------------------------------------------------------------
// Scores: softmax over each node-type's pair of edge types.
// ---------------------------------------------------------------------------
__global__ __launch_bounds__(64) void scores_k(
    const float* __restrict__ key, const float* __restrict__ q,
    float* __restrict__ wsc) {
  int l = threadIdx.x;
  float qv = q[l];
  float d[4];
#pragma unroll
  for (int m = 0; m < 4; ++m) {
    float p = qv * key[m * 64 + l];
#pragma unroll
    for (int off = 32; off; off >>= 1) p += __shfl_xor(p, off, 64);
    d[m] = p * (1.0f / NN);  // mean over nodes
  }
  if (l == 0) {
    {
      float mx = fmaxf(d[1], d[2]);
      float e1 = __expf(d[1] - mx), e2 = __expf(d[2] - mx);
      float inv = 1.f / (e1 + e2);
      wsc[1] = e1 * inv;
      wsc[2] = e2 * inv;
    }
    {
      float mx = fmaxf(d[0], d[3]);
      float e0 = __expf(d[0] - mx), e3 = __expf(d[3] - mx);
      float inv = 1.f / (e0 + e3);
      wsc[0] = e0 * inv;
      wsc[3] = e3 * inv;
    }
  }
}

__global__ __launch_bounds__(256) void combine_kernel(
    const float* __restrict__ out_et, const float* __restrict__ wsc,
    float* __restrict__ out) {
  size_t i4 = (size_t)blockIdx.x * 256 + threadIdx.x;  // float4 index over [2][N][16]
  if (i4 >= (size_t)2 * NN * 16) return;
  int type = i4 >= (size_t)NN * 16;
  size_t r4 = type ? i4 - (size_t)NN * 16 : i4;
  int m0 = type ? 0 : 1;
  int m1 = type ? 3 : 2;
  float s0 = wsc[m0], s1 = wsc[m1];
  float4 a = ((const float4*)out_et)[(size_t)m0 * NN * 16 + r4];
  float4 b = ((const float4*)out_et)[(size_t)m1 * NN * 16 + r4];
  float4 o;
  o.x = s0 * a.x + s1 * b.x;
  o.y = s0 * a.y + s1 * b.y;
  o.z = s0 * a.z + s1 * b.z;
  o.w = s0 * a.w + s1 * b.w;
  ((float4*)out)[i4] = o;
}

// ---------------------------------------------------------------------------
extern "C" void kernel_launch(void* const* d_in, const int* in_sizes, int n_in,
                              void* d_out, int out_size, void* d_ws,
                              size_t ws_size, hipStream_t stream) {
  const float* x_a = (const float*)d_in[0];
  const float* x_p = (const float*)d_in[1];
  const int* ei0 = (const int*)d_in[2];   // a->p
  const int* ei1 = (const int*)d_in[3];   // p->a
  const int* ei2 = (const int*)d_in[4];   // a->a
  const int* ei3 = (const int*)d_in[5];   // p->p
  const float* Wfa = (const float*)d_in[6];
  const float* bfa = (const float*)d_in[7];
  const float* Wfp = (const float*)d_in[8];
  const float* bfp = (const float*)d_in[9];
  const float* gWs = (const float*)d_in[10];
  const float* gWd = (const float*)d_in[11];
  const float* gas = (const float*)d_in[12];
  const float* gad = (const float*)d_in[13];
  const float* gb = (const float*)d_in[14];
  const float* Wk = (const float*)d_in[15];
  const float* bk = (const float*)d_in[16];
  const float* q = (const float*)d_in[17];
  float* out = (float*)d_out;
  (void)in_sizes; (void)n_in; (void)out_size; (void)ws_size;

  float* ws = (float*)d_ws;
  float* h = ws;                                     // 2*N*8
  float* alpha_s = h + (size_t)2 * NN * 8;           // 4*N*8
  float* out_et = alpha_s + (size_t)4 * NN * 8;      // 4*N*64
  float* Vs = out_et + (size_t)4 * NN * 64;          // 256
  float* Vd = Vs + 256;                              // 256
  float* key = Vd + 256;                             // 256
  float* wsc = key + 256;                            // 8 (4 used)
  int* counts = (int*)(wsc + 8);                     // 4*N
  int* rowptr = counts + (size_t)4 * NN;             // 4*N
  int* gcur = rowptr + (size_t)4 * NN;               // 4*NBUK (pad 1024)
  int* edge_src = gcur + 1024;                       // 4*NBUK*CAP = 7.02M ints

  hipMemsetAsync(gcur, 0, 1024 * sizeof(int), stream);
  hipMemsetAsync(key, 0, 256 * sizeof(float), stream);

  prep_V<<<1, 512, 0, stream>>>(gWs, gas, gWd, gad, Vs, Vd);
  fc_kernel<<<50000, 256, 0, stream>>>(x_a, x_p, Wfa, bfa, Wfp, bfp, h);
  node_alpha<<<(2 * NN + 255) / 256, 256, 0, stream>>>(h, Vs, alpha_s);
  bin_kernel<<<dim3(BINBLK, 4), 256, 0, stream>>>(ei0, ei1, ei2, ei3, gcur, edge_src);
  csr_kernel<<<dim3(NBUK, 4), 256, 0, stream>>>(gcur, edge_src, counts, rowptr);
  gat_pull<<<dim3((NN + 255) / 256, 4), 256, 0, stream>>>(h, alpha_s, rowptr, counts,
                                                          edge_src, gWs, Vd, gb, out_et);
  semantic_key<<<dim3(256, 4), 64, 0, stream>>>(out_et, Wk, bk, key);
  scores_k<<<1, 64, 0, stream>>>(key, q, wsc);
  combine_kernel<<<(2 * NN * 16 + 255) / 256, 256, 0, stream>>>(out_et, wsc, out);
}

// Round 3
// 655.159 us; speedup vs baseline: 1.9213x; 1.2215x over previous
//
#include <hip/hip_runtime.h>
#include <math.h>

#define NN 100000
#define EE 1600000
#define IND 256
#define SLOPE 0.2f

#define BUKBITS 9
#define BUKSZ 512            // nodes per bucket
#define NBUK 196             // ceil(NN/512)
#define CAP 8960             // bucket capacity: mean 8192 + 8*sigma(90)
#define CHUNK 4096           // edges per bin block
#define BINBLK 391           // ceil(EE/CHUNK)
#define NODEBLK 391          // ceil(NN/256)

// ---------------------------------------------------------------------------
// V matrices: alpha = h @ V,  V[et][k][h] = sum_c W[et][k][h*8+c] * a[et][h][c]
// ---------------------------------------------------------------------------
__global__ __launch_bounds__(512) void prep_V(
    const float* __restrict__ Ws, const float* __restrict__ as_,
    const float* __restrict__ Wd, const float* __restrict__ ad_,
    float* __restrict__ Vs, float* __restrict__ Vd) {
  int t = threadIdx.x;             // 0..511
  int half = t >> 8;
  int r = t & 255;
  int et = r >> 6, k = (r >> 3) & 7, hh = r & 7;
  const float* W = half ? Wd : Ws;
  const float* a = half ? ad_ : as_;
  float acc = 0.f;
#pragma unroll
  for (int c = 0; c < 8; ++c)
    acc += W[et * 512 + k * 64 + hh * 8 + c] * a[et * 64 + hh * 8 + c];
  (half ? Vd : Vs)[et * 64 + k * 8 + hh] = acc;
}

// ---------------------------------------------------------------------------
// FC: h[type][n][0..7] = x[n] @ Wfc + b.  One wave per row (coalesced 1KB/row).
// ---------------------------------------------------------------------------
__global__ __launch_bounds__(256) void fc_kernel(
    const float* __restrict__ xa, const float* __restrict__ xp,
    const float* __restrict__ Wa, const float* __restrict__ ba,
    const float* __restrict__ Wp, const float* __restrict__ bp,
    float* __restrict__ h) {
  int wid = (blockIdx.x * blockDim.x + threadIdx.x) >> 6;
  int lane = threadIdx.x & 63;
  if (wid >= 2 * NN) return;
  int type = wid >= NN;
  int row = type ? wid - NN : wid;
  const float* x = (type ? xp : xa) + (size_t)row * IND;
  const float* W = type ? Wp : Wa;
  const float* b = type ? bp : ba;
  float4 xv = *(const float4*)(x + lane * 4);
  float xs_[4] = {xv.x, xv.y, xv.z, xv.w};
  float acc[8];
#pragma unroll
  for (int c = 0; c < 8; ++c) acc[c] = 0.f;
#pragma unroll
  for (int j = 0; j < 4; ++j) {
    int k = lane * 4 + j;
    float xk = xs_[j];
#pragma unroll
    for (int c = 0; c < 8; ++c) acc[c] = fmaf(xk, W[k * 8 + c], acc[c]);
  }
#pragma unroll
  for (int c = 0; c < 8; ++c) {
#pragma unroll
    for (int off = 32; off; off >>= 1) acc[c] += __shfl_xor(acc[c], off, 64);
  }
  if (lane < 8) {
    float v = acc[0];
#pragma unroll
    for (int c = 1; c < 8; ++c)
      if (lane == c) v = acc[c];
    h[((size_t)type * NN + row) * 8 + lane] = v + b[lane];
  }
}

// ---------------------------------------------------------------------------
// Phase 1: bucket binning (dense writes, one global atomic per block-bucket).
// ---------------------------------------------------------------------------
__global__ __launch_bounds__(256) void bin_kernel(
    const int* __restrict__ e0, const int* __restrict__ e1,
    const int* __restrict__ e2, const int* __restrict__ e3,
    int* __restrict__ gcur, int* __restrict__ edge_src) {
  __shared__ int s_pack[CHUNK];
  __shared__ unsigned char s_buk[CHUNK];
  __shared__ int s_hist[NBUK], s_base[NBUK], s_cur[NBUK];
  int et = blockIdx.y;
  const int* ei = et == 0 ? e0 : et == 1 ? e1 : et == 2 ? e2 : e3;
  int t = threadIdx.x;
  for (int b = t; b < NBUK; b += 256) { s_hist[b] = 0; s_cur[b] = 0; }
  __syncthreads();
  int base = blockIdx.x * CHUNK;
#pragma unroll
  for (int r = 0; r < CHUNK / 256; ++r) {
    int i = r * 256 + t;
    int e = base + i;
    int bk = 255;
    if (e < EE) {
      int s = ei[e];
      int d = ei[EE + e];
      s_pack[i] = s | ((d & (BUKSZ - 1)) << 17);
      bk = d >> BUKBITS;
      atomicAdd(&s_hist[bk], 1);
    }
    s_buk[i] = (unsigned char)bk;
  }
  __syncthreads();
  for (int b = t; b < NBUK; b += 256)
    s_base[b] = atomicAdd(&gcur[et * NBUK + b], s_hist[b]);
  __syncthreads();
#pragma unroll
  for (int r = 0; r < CHUNK / 256; ++r) {
    int i = r * 256 + t;
    int bk = s_buk[i];
    if (bk != 255) {
      int pos = s_base[bk] + atomicAdd(&s_cur[bk], 1);
      if (pos < CAP)  // statistically impossible overflow guard
        edge_src[(size_t)(et * NBUK + bk) * CAP + pos] = s_pack[i];
    }
  }
}

// ---------------------------------------------------------------------------
// Phase 2: per-bucket CSR (LDS hist + scan + in-place scatter, dense writes).
// ---------------------------------------------------------------------------
__global__ __launch_bounds__(256) void csr_kernel(
    const int* __restrict__ gcur, int* __restrict__ edge_src,
    int* __restrict__ counts, int* __restrict__ rowptr) {
  __shared__ int s_data[CAP];
  __shared__ int s_hist[BUKSZ], s_off[BUKSZ], s_part[256];
  int buk = blockIdx.x, et = blockIdx.y, t = threadIdx.x;
  int bsz = gcur[et * NBUK + buk];
  if (bsz > CAP) bsz = CAP;
  int ebase = (et * NBUK + buk) * CAP;
  for (int j = t; j < BUKSZ; j += 256) s_hist[j] = 0;
  __syncthreads();
  for (int i = t; i < bsz; i += 256) {
    int v = edge_src[ebase + i];
    s_data[i] = v;
    atomicAdd(&s_hist[v >> 17], 1);
  }
  __syncthreads();
  int b2 = t * 2;
  int a0 = s_hist[b2], a1 = s_hist[b2 + 1];
  int tot = a0 + a1;
  s_part[t] = tot;
  __syncthreads();
#pragma unroll
  for (int off = 1; off < 256; off <<= 1) {
    int v = (t >= off) ? s_part[t - off] : 0;
    __syncthreads();
    s_part[t] += v;
    __syncthreads();
  }
  int ex = s_part[t] - tot;
  s_off[b2] = ex;
  s_off[b2 + 1] = ex + a0;
  __syncthreads();
  for (int j = t; j < BUKSZ; j += 256) {
    int node = buk * BUKSZ + j;
    if (node < NN) {
      counts[(size_t)et * NN + node] = s_hist[j];
      rowptr[(size_t)et * NN + node] = ebase + s_off[j];
    }
  }
  __syncthreads();
  for (int i = t; i < bsz; i += 256) {
    int v = s_data[i];
    int pos = atomicAdd(&s_off[v >> 17], 1);
    edge_src[ebase + pos] = v & 0x1FFFF;
  }
}

// ---------------------------------------------------------------------------
// GAT pull: one thread per dst node. alpha_s recomputed IN-REGISTER per edge
// (64 FMA w/ uniform Vs in SGPRs) so the only random gather is h_src (32B,
// 3.2MB hot set). 1-D grid with XCD src-type affinity: blocks whose
// blockIdx%8 < 4 (XCDs 0-3) handle a-src edge types {0,2}; XCDs 4-7 handle
// p-src types {1,3} -> each XCD's 4MB L2 holds one 3.2MB h slab.
// ---------------------------------------------------------------------------
__global__ __launch_bounds__(256) void gat_pull(
    const float* __restrict__ h,
    const int* __restrict__ rowptr, const int* __restrict__ counts,
    const int* __restrict__ edge_src,
    const float* __restrict__ Wsrc_all, const float* __restrict__ Vs,
    const float* __restrict__ Vd,
    const float* __restrict__ bias_all, float* __restrict__ out_et) {
  int b = blockIdx.x;
  int xcd = b & 7;
  int g_ = xcd >> 2;                      // src type this XCD owns
  int sid = (b >> 3) * 4 + (xcd & 3);     // 0..783
  if (sid >= 2 * NODEBLK) return;
  int et = (sid < NODEBLK) ? g_ : g_ + 2; // a:{0,2}  p:{1,3}
  int nb = (sid < NODEBLK) ? sid : sid - NODEBLK;
  int n = nb * 256 + threadIdx.x;
  if (n >= NN) return;
  int st = et & 1;                           // src type: 0=a,1=p
  int dt = (et & 1) ^ (et < 2 ? 1 : 0);      // dst type
  const float* hsrc = h + (size_t)st * NN * 8;
  const float* hdst = h + (size_t)dt * NN * 8;
  const float* Ws = Wsrc_all + et * 512;
  const float* Vse = Vs + et * 64;
  const float* Vde = Vd + et * 64;
  const float* bs = bias_all + et * 64;

  float4 hd0 = *(const float4*)(hdst + (size_t)n * 8);
  float4 hd1 = *(const float4*)(hdst + (size_t)n * 8 + 4);
  float hd[8] = {hd0.x, hd0.y, hd0.z, hd0.w, hd1.x, hd1.y, hd1.z, hd1.w};
  float ad[8];
#pragma unroll
  for (int hh = 0; hh < 8; ++hh) {
    float acc = 0.f;
#pragma unroll
    for (int k = 0; k < 8; ++k) acc = fmaf(hd[k], Vde[k * 8 + hh], acc);
    ad[hh] = acc;
  }
  float g[64];
  float z[8];
#pragma unroll
  for (int i = 0; i < 64; ++i) g[i] = 0.f;
#pragma unroll
  for (int hh = 0; hh < 8; ++hh) z[hh] = 0.f;

  int start = rowptr[(size_t)et * NN + n];
  int deg = counts[(size_t)et * NN + n];
  const int* es = edge_src + start;
  for (int i = 0; i < deg; ++i) {
    int s = es[i];
    float4 a0 = *(const float4*)(hsrc + (size_t)s * 8);
    float4 a1 = *(const float4*)(hsrc + (size_t)s * 8 + 4);
    float hs[8] = {a0.x, a0.y, a0.z, a0.w, a1.x, a1.y, a1.z, a1.w};
#pragma unroll
    for (int hh = 0; hh < 8; ++hh) {
      // alpha_s recomputed in-register: 8 FMA (Vs uniform -> SGPR operands)
      float e = ad[hh];
#pragma unroll
      for (int k = 0; k < 8; ++k) e = fmaf(hs[k], Vse[k * 8 + hh], e);
      e = e > 0.f ? e : SLOPE * e;
      float w = __expf(e);
      z[hh] += w;
#pragma unroll
      for (int k = 0; k < 8; ++k) g[hh * 8 + k] = fmaf(w, hs[k], g[hh * 8 + k]);
    }
  }

  float* op = out_et + ((size_t)et * NN + n) * 64;
#pragma unroll
  for (int hh = 0; hh < 8; ++hh) {
    float rz = 1.f / (z[hh] + 1e-16f);
    float o[8];
#pragma unroll
    for (int c = 0; c < 8; ++c) {
      float acc = 0.f;
#pragma unroll
      for (int k = 0; k < 8; ++k)
        acc = fmaf(g[hh * 8 + k], Ws[k * 64 + hh * 8 + c], acc);
      o[c] = acc * rz + bs[hh * 8 + c];
    }
    *(float4*)(op + hh * 8) = make_float4(o[0], o[1], o[2], o[3]);
    *(float4*)(op + hh * 8 + 4) = make_float4(o[4], o[5], o[6], o[7]);
  }
}

// ---------------------------------------------------------------------------
// Semantic attention keys: key[et] = sum_n tanh(out_et[n] @ Wk + bk)
// ---------------------------------------------------------------------------
__global__ __launch_bounds__(64) void semantic_key(
    const float* __restrict__ out_et, const float* __restrict__ Wk,
    const float* __restrict__ bk, float* __restrict__ key) {
  __shared__ float srow[64 * 64];  // srow[k*64 + lane]
  int m = blockIdx.y;
  int lane = threadIdx.x;
  const float* base = out_et + (size_t)m * NN * 64;
  float ka[64];
#pragma unroll
  for (int j = 0; j < 64; ++j) ka[j] = 0.f;

  for (int n = blockIdx.x * 64 + lane; n < NN; n += gridDim.x * 64) {
    const float* row = base + (size_t)n * 64;
#pragma unroll
    for (int k4 = 0; k4 < 16; ++k4) {
      float4 v = ((const float4*)row)[k4];
      srow[(k4 * 4 + 0) * 64 + lane] = v.x;
      srow[(k4 * 4 + 1) * 64 + lane] = v.y;
      srow[(k4 * 4 + 2) * 64 + lane] = v.z;
      srow[(k4 * 4 + 3) * 64 + lane] = v.w;
    }
    float acc[64];
#pragma unroll
    for (int j = 0; j < 64; ++j) acc[j] = 0.f;
    for (int k = 0; k < 64; ++k) {
      float rk = srow[k * 64 + lane];
#pragma unroll
      for (int j = 0; j < 64; ++j) acc[j] = fmaf(rk, Wk[k * 64 + j], acc[j]);
    }
#pragma unroll
    for (int j = 0; j < 64; ++j) {
      float x = acc[j] + bk[j];
      float t = 1.f - 2.f / (__expf(2.f * x) + 1.f);  // tanh
      ka[j] += t;
    }
  }
#pragma unroll
  for (int j = 0; j < 64; ++j) {
#pragma unroll
    for (int off = 32; off; off >>= 1) ka[j] += __shfl_xor(ka[j], off, 64);
  }
  if (lane == 0) {
#pragma unroll
    for (int j = 0; j < 64; ++j) atomicAdd(&key[m * 64 + j], ka[j]);
  }
}

// ---------------------------------------------------------------------------
// Scores: softmax over each node-type's pair of edge types.
// ---------------------------------------------------------------------------
__global__ __launch_bounds__(64) void scores_k(
    const float* __restrict__ key, const float* __restrict__ q,
    float* __restrict__ wsc) {
  int l = threadIdx.x;
  float qv = q[l];
  float d[4];
#pragma unroll
  for (int m = 0; m < 4; ++m) {
    float p = qv * key[m * 64 + l];
#pragma unroll
    for (int off = 32; off; off >>= 1) p += __shfl_xor(p, off, 64);
    d[m] = p * (1.0f / NN);  // mean over nodes
  }
  if (l == 0) {
    {
      float mx = fmaxf(d[1], d[2]);
      float e1 = __expf(d[1] - mx), e2 = __expf(d[2] - mx);
      float inv = 1.f / (e1 + e2);
      wsc[1] = e1 * inv;
      wsc[2] = e2 * inv;
    }
    {
      float mx = fmaxf(d[0], d[3]);
      float e0 = __expf(d[0] - mx), e3 = __expf(d[3] - mx);
      float inv = 1.f / (e0 + e3);
      wsc[0] = e0 * inv;
      wsc[3] = e3 * inv;
    }
  }
}

__global__ __launch_bounds__(256) void combine_kernel(
    const float* __restrict__ out_et, const float* __restrict__ wsc,
    float* __restrict__ out) {
  size_t i4 = (size_t)blockIdx.x * 256 + threadIdx.x;  // float4 index over [2][N][16]
  if (i4 >= (size_t)2 * NN * 16) return;
  int type = i4 >= (size_t)NN * 16;
  size_t r4 = type ? i4 - (size_t)NN * 16 : i4;
  int m0 = type ? 0 : 1;
  int m1 = type ? 3 : 2;
  float s0 = wsc[m0], s1 = wsc[m1];
  float4 a = ((const float4*)out_et)[(size_t)m0 * NN * 16 + r4];
  float4 b = ((const float4*)out_et)[(size_t)m1 * NN * 16 + r4];
  float4 o;
  o.x = s0 * a.x + s1 * b.x;
  o.y = s0 * a.y + s1 * b.y;
  o.z = s0 * a.z + s1 * b.z;
  o.w = s0 * a.w + s1 * b.w;
  ((float4*)out)[i4] = o;
}

// ---------------------------------------------------------------------------
extern "C" void kernel_launch(void* const* d_in, const int* in_sizes, int n_in,
                              void* d_out, int out_size, void* d_ws,
                              size_t ws_size, hipStream_t stream) {
  const float* x_a = (const float*)d_in[0];
  const float* x_p = (const float*)d_in[1];
  const int* ei0 = (const int*)d_in[2];   // a->p
  const int* ei1 = (const int*)d_in[3];   // p->a
  const int* ei2 = (const int*)d_in[4];   // a->a
  const int* ei3 = (const int*)d_in[5];   // p->p
  const float* Wfa = (const float*)d_in[6];
  const float* bfa = (const float*)d_in[7];
  const float* Wfp = (const float*)d_in[8];
  const float* bfp = (const float*)d_in[9];
  const float* gWs = (const float*)d_in[10];
  const float* gWd = (const float*)d_in[11];
  const float* gas = (const float*)d_in[12];
  const float* gad = (const float*)d_in[13];
  const float* gb = (const float*)d_in[14];
  const float* Wk = (const float*)d_in[15];
  const float* bk = (const float*)d_in[16];
  const float* q = (const float*)d_in[17];
  float* out = (float*)d_out;
  (void)in_sizes; (void)n_in; (void)out_size; (void)ws_size;

  float* ws = (float*)d_ws;
  float* h = ws;                                     // 2*N*8
  float* out_et = h + (size_t)2 * NN * 8;            // 4*N*64
  float* Vs = out_et + (size_t)4 * NN * 64;          // 256
  float* Vd = Vs + 256;                              // 256
  float* key = Vd + 256;                             // 256
  float* wsc = key + 256;                            // 8 (4 used)
  int* counts = (int*)(wsc + 8);                     // 4*N
  int* rowptr = counts + (size_t)4 * NN;             // 4*N
  int* gcur = rowptr + (size_t)4 * NN;               // 4*NBUK (pad 1024)
  int* edge_src = gcur + 1024;                       // 4*NBUK*CAP ints

  hipMemsetAsync(gcur, 0, 1024 * sizeof(int), stream);
  hipMemsetAsync(key, 0, 256 * sizeof(float), stream);

  prep_V<<<1, 512, 0, stream>>>(gWs, gas, gWd, gad, Vs, Vd);
  fc_kernel<<<50000, 256, 0, stream>>>(x_a, x_p, Wfa, bfa, Wfp, bfp, h);
  bin_kernel<<<dim3(BINBLK, 4), 256, 0, stream>>>(ei0, ei1, ei2, ei3, gcur, edge_src);
  csr_kernel<<<dim3(NBUK, 4), 256, 0, stream>>>(gcur, edge_src, counts, rowptr);
  gat_pull<<<1568, 256, 0, stream>>>(h, rowptr, counts, edge_src,
                                     gWs, Vs, Vd, gb, out_et);
  semantic_key<<<dim3(256, 4), 64, 0, stream>>>(out_et, Wk, bk, key);
  scores_k<<<1, 64, 0, stream>>>(key, q, wsc);
  combine_kernel<<<(2 * NN * 16 + 255) / 256, 256, 0, stream>>>(out_et, wsc, out);
}

// Round 4
// 503.622 us; speedup vs baseline: 2.4994x; 1.3009x over previous
//
#include <hip/hip_runtime.h>
#include <math.h>

#define NN 100000
#define EE 1600000
#define IND 256
#define SLOPE 0.2f

#define BUKBITS 9
#define BUKSZ 512            // nodes per bucket
#define NBUK 196             // ceil(NN/512)
#define CAP 8960             // bucket capacity: mean 8192 + 8*sigma(90)
#define CHUNK 4096           // edges per bin block
#define BINBLK 391           // ceil(EE/CHUNK)
#define NODEBLK 391          // ceil(NN/256)
#define SKW 1024             // semantic_key: waves per m-slice (256 blk x 4)

// ---------------------------------------------------------------------------
// V matrices: alpha = h @ V,  V[et][k][h] = sum_c W[et][k][h*8+c] * a[et][h][c]
// ---------------------------------------------------------------------------
__global__ __launch_bounds__(512) void prep_V(
    const float* __restrict__ Ws, const float* __restrict__ as_,
    const float* __restrict__ Wd, const float* __restrict__ ad_,
    float* __restrict__ Vs, float* __restrict__ Vd) {
  int t = threadIdx.x;             // 0..511
  int half = t >> 8;
  int r = t & 255;
  int et = r >> 6, k = (r >> 3) & 7, hh = r & 7;
  const float* W = half ? Wd : Ws;
  const float* a = half ? ad_ : as_;
  float acc = 0.f;
#pragma unroll
  for (int c = 0; c < 8; ++c)
    acc += W[et * 512 + k * 64 + hh * 8 + c] * a[et * 64 + hh * 8 + c];
  (half ? Vd : Vs)[et * 64 + k * 8 + hh] = acc;
}

// ---------------------------------------------------------------------------
// FC: h[type][n][0..7] = x[n] @ Wfc + b.  One wave per row (coalesced 1KB/row).
// ---------------------------------------------------------------------------
__global__ __launch_bounds__(256) void fc_kernel(
    const float* __restrict__ xa, const float* __restrict__ xp,
    const float* __restrict__ Wa, const float* __restrict__ ba,
    const float* __restrict__ Wp, const float* __restrict__ bp,
    float* __restrict__ h) {
  int wid = (blockIdx.x * blockDim.x + threadIdx.x) >> 6;
  int lane = threadIdx.x & 63;
  if (wid >= 2 * NN) return;
  int type = wid >= NN;
  int row = type ? wid - NN : wid;
  const float* x = (type ? xp : xa) + (size_t)row * IND;
  const float* W = type ? Wp : Wa;
  const float* b = type ? bp : ba;
  float4 xv = *(const float4*)(x + lane * 4);
  float xs_[4] = {xv.x, xv.y, xv.z, xv.w};
  float acc[8];
#pragma unroll
  for (int c = 0; c < 8; ++c) acc[c] = 0.f;
#pragma unroll
  for (int j = 0; j < 4; ++j) {
    int k = lane * 4 + j;
    float xk = xs_[j];
#pragma unroll
    for (int c = 0; c < 8; ++c) acc[c] = fmaf(xk, W[k * 8 + c], acc[c]);
  }
#pragma unroll
  for (int c = 0; c < 8; ++c) {
#pragma unroll
    for (int off = 32; off; off >>= 1) acc[c] += __shfl_xor(acc[c], off, 64);
  }
  if (lane < 8) {
    float v = acc[0];
#pragma unroll
    for (int c = 1; c < 8; ++c)
      if (lane == c) v = acc[c];
    h[((size_t)type * NN + row) * 8 + lane] = v + b[lane];
  }
}

// ---------------------------------------------------------------------------
// Phase 1: bucket binning (dense writes, one global atomic per block-bucket).
// ---------------------------------------------------------------------------
__global__ __launch_bounds__(256) void bin_kernel(
    const int* __restrict__ e0, const int* __restrict__ e1,
    const int* __restrict__ e2, const int* __restrict__ e3,
    int* __restrict__ gcur, int* __restrict__ edge_src) {
  __shared__ int s_pack[CHUNK];
  __shared__ unsigned char s_buk[CHUNK];
  __shared__ int s_hist[NBUK], s_base[NBUK], s_cur[NBUK];
  int et = blockIdx.y;
  const int* ei = et == 0 ? e0 : et == 1 ? e1 : et == 2 ? e2 : e3;
  int t = threadIdx.x;
  for (int b = t; b < NBUK; b += 256) { s_hist[b] = 0; s_cur[b] = 0; }
  __syncthreads();
  int base = blockIdx.x * CHUNK;
#pragma unroll
  for (int r = 0; r < CHUNK / 256; ++r) {
    int i = r * 256 + t;
    int e = base + i;
    int bk = 255;
    if (e < EE) {
      int s = ei[e];
      int d = ei[EE + e];
      s_pack[i] = s | ((d & (BUKSZ - 1)) << 17);
      bk = d >> BUKBITS;
      atomicAdd(&s_hist[bk], 1);
    }
    s_buk[i] = (unsigned char)bk;
  }
  __syncthreads();
  for (int b = t; b < NBUK; b += 256)
    s_base[b] = atomicAdd(&gcur[et * NBUK + b], s_hist[b]);
  __syncthreads();
#pragma unroll
  for (int r = 0; r < CHUNK / 256; ++r) {
    int i = r * 256 + t;
    int bk = s_buk[i];
    if (bk != 255) {
      int pos = s_base[bk] + atomicAdd(&s_cur[bk], 1);
      if (pos < CAP)  // statistically impossible overflow guard
        edge_src[(size_t)(et * NBUK + bk) * CAP + pos] = s_pack[i];
    }
  }
}

// ---------------------------------------------------------------------------
// Phase 2: per-bucket CSR (LDS hist + scan + in-place scatter, dense writes).
// ---------------------------------------------------------------------------
__global__ __launch_bounds__(256) void csr_kernel(
    const int* __restrict__ gcur, int* __restrict__ edge_src,
    int* __restrict__ counts, int* __restrict__ rowptr) {
  __shared__ int s_data[CAP];
  __shared__ int s_hist[BUKSZ], s_off[BUKSZ], s_part[256];
  int buk = blockIdx.x, et = blockIdx.y, t = threadIdx.x;
  int bsz = gcur[et * NBUK + buk];
  if (bsz > CAP) bsz = CAP;
  int ebase = (et * NBUK + buk) * CAP;
  for (int j = t; j < BUKSZ; j += 256) s_hist[j] = 0;
  __syncthreads();
  for (int i = t; i < bsz; i += 256) {
    int v = edge_src[ebase + i];
    s_data[i] = v;
    atomicAdd(&s_hist[v >> 17], 1);
  }
  __syncthreads();
  int b2 = t * 2;
  int a0 = s_hist[b2], a1 = s_hist[b2 + 1];
  int tot = a0 + a1;
  s_part[t] = tot;
  __syncthreads();
#pragma unroll
  for (int off = 1; off < 256; off <<= 1) {
    int v = (t >= off) ? s_part[t - off] : 0;
    __syncthreads();
    s_part[t] += v;
    __syncthreads();
  }
  int ex = s_part[t] - tot;
  s_off[b2] = ex;
  s_off[b2 + 1] = ex + a0;
  __syncthreads();
  for (int j = t; j < BUKSZ; j += 256) {
    int node = buk * BUKSZ + j;
    if (node < NN) {
      counts[(size_t)et * NN + node] = s_hist[j];
      rowptr[(size_t)et * NN + node] = ebase + s_off[j];
    }
  }
  __syncthreads();
  for (int i = t; i < bsz; i += 256) {
    int v = s_data[i];
    int pos = atomicAdd(&s_off[v >> 17], 1);
    edge_src[ebase + pos] = v & 0x1FFFF;
  }
}

// ---------------------------------------------------------------------------
// GAT pull: one thread per dst node. alpha_s recomputed in-register; only
// random gather is h_src (3.2MB/XCD via src-type XCD affinity).
// ---------------------------------------------------------------------------
__global__ __launch_bounds__(256) void gat_pull(
    const float* __restrict__ h,
    const int* __restrict__ rowptr, const int* __restrict__ counts,
    const int* __restrict__ edge_src,
    const float* __restrict__ Wsrc_all, const float* __restrict__ Vs,
    const float* __restrict__ Vd,
    const float* __restrict__ bias_all, float* __restrict__ out_et) {
  int b = blockIdx.x;
  int xcd = b & 7;
  int g_ = xcd >> 2;                      // src type this XCD owns
  int sid = (b >> 3) * 4 + (xcd & 3);     // 0..783
  if (sid >= 2 * NODEBLK) return;
  int et = (sid < NODEBLK) ? g_ : g_ + 2; // a:{0,2}  p:{1,3}
  int nb = (sid < NODEBLK) ? sid : sid - NODEBLK;
  int n = nb * 256 + threadIdx.x;
  if (n >= NN) return;
  int st = et & 1;                           // src type: 0=a,1=p
  int dt = (et & 1) ^ (et < 2 ? 1 : 0);      // dst type
  const float* hsrc = h + (size_t)st * NN * 8;
  const float* hdst = h + (size_t)dt * NN * 8;
  const float* Ws = Wsrc_all + et * 512;
  const float* Vse = Vs + et * 64;
  const float* Vde = Vd + et * 64;
  const float* bs = bias_all + et * 64;

  float4 hd0 = *(const float4*)(hdst + (size_t)n * 8);
  float4 hd1 = *(const float4*)(hdst + (size_t)n * 8 + 4);
  float hd[8] = {hd0.x, hd0.y, hd0.z, hd0.w, hd1.x, hd1.y, hd1.z, hd1.w};
  float ad[8];
#pragma unroll
  for (int hh = 0; hh < 8; ++hh) {
    float acc = 0.f;
#pragma unroll
    for (int k = 0; k < 8; ++k) acc = fmaf(hd[k], Vde[k * 8 + hh], acc);
    ad[hh] = acc;
  }
  float g[64];
  float z[8];
#pragma unroll
  for (int i = 0; i < 64; ++i) g[i] = 0.f;
#pragma unroll
  for (int hh = 0; hh < 8; ++hh) z[hh] = 0.f;

  int start = rowptr[(size_t)et * NN + n];
  int deg = counts[(size_t)et * NN + n];
  const int* es = edge_src + start;
  for (int i = 0; i < deg; ++i) {
    int s = es[i];
    float4 a0 = *(const float4*)(hsrc + (size_t)s * 8);
    float4 a1 = *(const float4*)(hsrc + (size_t)s * 8 + 4);
    float hs[8] = {a0.x, a0.y, a0.z, a0.w, a1.x, a1.y, a1.z, a1.w};
#pragma unroll
    for (int hh = 0; hh < 8; ++hh) {
      float e = ad[hh];
#pragma unroll
      for (int k = 0; k < 8; ++k) e = fmaf(hs[k], Vse[k * 8 + hh], e);
      e = e > 0.f ? e : SLOPE * e;
      float w = __expf(e);
      z[hh] += w;
#pragma unroll
      for (int k = 0; k < 8; ++k) g[hh * 8 + k] = fmaf(w, hs[k], g[hh * 8 + k]);
    }
  }

  float* op = out_et + ((size_t)et * NN + n) * 64;
#pragma unroll
  for (int hh = 0; hh < 8; ++hh) {
    float rz = 1.f / (z[hh] + 1e-16f);
    float o[8];
#pragma unroll
    for (int c = 0; c < 8; ++c) {
      float acc = 0.f;
#pragma unroll
      for (int k = 0; k < 8; ++k)
        acc = fmaf(g[hh * 8 + k], Ws[k * 64 + hh * 8 + c], acc);
      o[c] = acc * rz + bs[hh * 8 + c];
    }
    *(float4*)(op + hh * 8) = make_float4(o[0], o[1], o[2], o[3]);
    *(float4*)(op + hh * 8 + 4) = make_float4(o[4], o[5], o[6], o[7]);
  }
}

// ---------------------------------------------------------------------------
// Semantic attention keys: key[m][j] = sum_n tanh(out_et[m][n] @ Wk + bk)[j]
// Lane = output column j (Wk column held in 64 VGPRs, loaded once).
// Wave = node; row address made wave-uniform via readfirstlane so row loads
// are single-line scalar/uniform fetches. 4 acc chains for FMA ILP.
// ---------------------------------------------------------------------------
__global__ __launch_bounds__(256) void semantic_key(
    const float* __restrict__ out_et, const float* __restrict__ Wk,
    const float* __restrict__ bk, float* __restrict__ key) {
  __shared__ float s_red[256];
  int m = blockIdx.y;
  int lane = threadIdx.x & 63;
  float wcol[64];
#pragma unroll
  for (int k = 0; k < 64; ++k) wcol[k] = Wk[k * 64 + lane];
  float bj = bk[lane];
  float ka = 0.f;
  const float* base = out_et + (size_t)m * NN * 64;
  int gw = blockIdx.x * 4 + (threadIdx.x >> 6);
  for (int n = gw; n < NN; n += SKW) {
    int nu = __builtin_amdgcn_readfirstlane(n);
    const float* row = base + (size_t)nu * 64;
    float a0 = bj, a1 = 0.f, a2 = 0.f, a3 = 0.f;
#pragma unroll
    for (int k4 = 0; k4 < 16; ++k4) {
      float4 r = *(const float4*)(row + k4 * 4);
      a0 = fmaf(r.x, wcol[k4 * 4 + 0], a0);
      a1 = fmaf(r.y, wcol[k4 * 4 + 1], a1);
      a2 = fmaf(r.z, wcol[k4 * 4 + 2], a2);
      a3 = fmaf(r.w, wcol[k4 * 4 + 3], a3);
    }
    float x = (a0 + a1) + (a2 + a3);
    float t = 1.f - 2.f / (__expf(2.f * x) + 1.f);  // tanh
    ka += t;
  }
  s_red[threadIdx.x] = ka;
  __syncthreads();
  if (threadIdx.x < 64) {
    float v = s_red[lane] + s_red[64 + lane] + s_red[128 + lane] +
              s_red[192 + lane];
    atomicAdd(&key[m * 64 + lane], v);
  }
}

// ---------------------------------------------------------------------------
// Scores: softmax over each node-type's pair of edge types.
// ---------------------------------------------------------------------------
__global__ __launch_bounds__(64) void scores_k(
    const float* __restrict__ key, const float* __restrict__ q,
    float* __restrict__ wsc) {
  int l = threadIdx.x;
  float qv = q[l];
  float d[4];
#pragma unroll
  for (int m = 0; m < 4; ++m) {
    float p = qv * key[m * 64 + l];
#pragma unroll
    for (int off = 32; off; off >>= 1) p += __shfl_xor(p, off, 64);
    d[m] = p * (1.0f / NN);  // mean over nodes
  }
  if (l == 0) {
    {
      float mx = fmaxf(d[1], d[2]);
      float e1 = __expf(d[1] - mx), e2 = __expf(d[2] - mx);
      float inv = 1.f / (e1 + e2);
      wsc[1] = e1 * inv;
      wsc[2] = e2 * inv;
    }
    {
      float mx = fmaxf(d[0], d[3]);
      float e0 = __expf(d[0] - mx), e3 = __expf(d[3] - mx);
      float inv = 1.f / (e0 + e3);
      wsc[0] = e0 * inv;
      wsc[3] = e3 * inv;
    }
  }
}

__global__ __launch_bounds__(256) void combine_kernel(
    const float* __restrict__ out_et, const float* __restrict__ wsc,
    float* __restrict__ out) {
  size_t i4 = (size_t)blockIdx.x * 256 + threadIdx.x;  // float4 index over [2][N][16]
  if (i4 >= (size_t)2 * NN * 16) return;
  int type = i4 >= (size_t)NN * 16;
  size_t r4 = type ? i4 - (size_t)NN * 16 : i4;
  int m0 = type ? 0 : 1;
  int m1 = type ? 3 : 2;
  float s0 = wsc[m0], s1 = wsc[m1];
  float4 a = ((const float4*)out_et)[(size_t)m0 * NN * 16 + r4];
  float4 b = ((const float4*)out_et)[(size_t)m1 * NN * 16 + r4];
  float4 o;
  o.x = s0 * a.x + s1 * b.x;
  o.y = s0 * a.y + s1 * b.y;
  o.z = s0 * a.z + s1 * b.z;
  o.w = s0 * a.w + s1 * b.w;
  ((float4*)out)[i4] = o;
}

// ---------------------------------------------------------------------------
extern "C" void kernel_launch(void* const* d_in, const int* in_sizes, int n_in,
                              void* d_out, int out_size, void* d_ws,
                              size_t ws_size, hipStream_t stream) {
  const float* x_a = (const float*)d_in[0];
  const float* x_p = (const float*)d_in[1];
  const int* ei0 = (const int*)d_in[2];   // a->p
  const int* ei1 = (const int*)d_in[3];   // p->a
  const int* ei2 = (const int*)d_in[4];   // a->a
  const int* ei3 = (const int*)d_in[5];   // p->p
  const float* Wfa = (const float*)d_in[6];
  const float* bfa = (const float*)d_in[7];
  const float* Wfp = (const float*)d_in[8];
  const float* bfp = (const float*)d_in[9];
  const float* gWs = (const float*)d_in[10];
  const float* gWd = (const float*)d_in[11];
  const float* gas = (const float*)d_in[12];
  const float* gad = (const float*)d_in[13];
  const float* gb = (const float*)d_in[14];
  const float* Wk = (const float*)d_in[15];
  const float* bk = (const float*)d_in[16];
  const float* q = (const float*)d_in[17];
  float* out = (float*)d_out;
  (void)in_sizes; (void)n_in; (void)out_size; (void)ws_size;

  float* ws = (float*)d_ws;
  float* h = ws;                                     // 2*N*8
  float* out_et = h + (size_t)2 * NN * 8;            // 4*N*64
  float* Vs = out_et + (size_t)4 * NN * 64;          // 256
  float* Vd = Vs + 256;                              // 256
  float* key = Vd + 256;                             // 256
  float* wsc = key + 256;                            // 8 (4 used)
  int* counts = (int*)(wsc + 8);                     // 4*N
  int* rowptr = counts + (size_t)4 * NN;             // 4*N
  int* gcur = rowptr + (size_t)4 * NN;               // 4*NBUK (pad 1024)
  int* edge_src = gcur + 1024;                       // 4*NBUK*CAP ints

  hipMemsetAsync(gcur, 0, 1024 * sizeof(int), stream);
  hipMemsetAsync(key, 0, 256 * sizeof(float), stream);

  prep_V<<<1, 512, 0, stream>>>(gWs, gas, gWd, gad, Vs, Vd);
  fc_kernel<<<50000, 256, 0, stream>>>(x_a, x_p, Wfa, bfa, Wfp, bfp, h);
  bin_kernel<<<dim3(BINBLK, 4), 256, 0, stream>>>(ei0, ei1, ei2, ei3, gcur, edge_src);
  csr_kernel<<<dim3(NBUK, 4), 256, 0, stream>>>(gcur, edge_src, counts, rowptr);
  gat_pull<<<1568, 256, 0, stream>>>(h, rowptr, counts, edge_src,
                                     gWs, Vs, Vd, gb, out_et);
  semantic_key<<<dim3(256, 4), 256, 0, stream>>>(out_et, Wk, bk, key);
  scores_k<<<1, 64, 0, stream>>>(key, q, wsc);
  combine_kernel<<<(2 * NN * 16 + 255) / 256, 256, 0, stream>>>(out_et, wsc, out);
}

// Round 5
// 430.673 us; speedup vs baseline: 2.9228x; 1.1694x over previous
//
#include <hip/hip_runtime.h>
#include <math.h>

#define NN 100000
#define EE 1600000
#define IND 256
#define SLOPE 0.2f

#define BUKBITS 9
#define BUKSZ 512            // nodes per bucket
#define NBUK 196             // ceil(NN/512)
#define CAP 8960             // bucket capacity: mean 8192 + 8*sigma(90)
#define CHUNK 4096           // edges per bin block
#define BINBLK 391           // ceil(EE/CHUNK)
#define NODEBLK 391          // ceil(NN/256)
#define SKW 1024             // semantic_key: waves per m-slice (256 blk x 4)
#define FCTILES 3125         // 200000 rows / 64 rows per tile

// ---------------------------------------------------------------------------
// V matrices: alpha = h @ V,  V[et][k][h] = sum_c W[et][k][h*8+c] * a[et][h][c]
// ---------------------------------------------------------------------------
__global__ __launch_bounds__(512) void prep_V(
    const float* __restrict__ Ws, const float* __restrict__ as_,
    const float* __restrict__ Wd, const float* __restrict__ ad_,
    float* __restrict__ Vs, float* __restrict__ Vd) {
  int t = threadIdx.x;             // 0..511
  int half = t >> 8;
  int r = t & 255;
  int et = r >> 6, k = (r >> 3) & 7, hh = r & 7;
  const float* W = half ? Wd : Ws;
  const float* a = half ? ad_ : as_;
  float acc = 0.f;
#pragma unroll
  for (int c = 0; c < 8; ++c)
    acc += W[et * 512 + k * 64 + hh * 8 + c] * a[et * 64 + hh * 8 + c];
  (half ? Vd : Vs)[et * 64 + k * 8 + hh] = acc;
}

// ---------------------------------------------------------------------------
// FC: h[tr][0..7] = x[tr] @ Wfc + b, rows 0..2N-1 (a then p).
// LDS-tiled: 64-row tiles, W strips cached in 64 VGPRs, rotation-butterfly
// 8-way reduce (lane j ends holding column j). Memory-bound by design.
// ---------------------------------------------------------------------------
__global__ __launch_bounds__(256, 2) void fc_kernel(
    const float* __restrict__ xa, const float* __restrict__ xp,
    const float* __restrict__ Wa, const float* __restrict__ ba,
    const float* __restrict__ Wp, const float* __restrict__ bp,
    float* __restrict__ h) {
  __shared__ float s_x[64 * 260];
  int t = threadIdx.x;
  int base_row = blockIdx.x * 64;
  // ---- stage 64 rows (64 KB), fully coalesced, 16 float4 per thread ----
#pragma unroll
  for (int i = 0; i < 16; ++i) {
    int flat = i * 256 + t;            // float4 index in tile (0..4095)
    int r = flat >> 6;                 // row in tile (64 float4 per row)
    int c4 = flat & 63;
    int grow = base_row + r;
    const float* src = (grow < NN) ? (xa + (size_t)grow * IND)
                                   : (xp + (size_t)(grow - NN) * IND);
    float4 v = *(const float4*)(src + c4 * 4);
    *(float4*)(&s_x[r * 260 + c4 * 4]) = v;
  }
  __syncthreads();
  // ---- compute: wave w owns rows w*16..w*16+15 (type is wave-uniform) ----
  int w = t >> 6;
  int lane = t & 63;
  int rr = lane >> 3;                  // row-sub 0..7
  int j = lane & 7;                    // k-octet 0..7
  int wrow0 = base_row + w * 16;
  int type = wrow0 >= NN;
  const float* W = type ? Wp : Wa;
  const float* b = type ? bp : ba;
  float acc[2][8];
#pragma unroll
  for (int rt = 0; rt < 2; ++rt)
#pragma unroll
    for (int c = 0; c < 8; ++c) acc[rt][c] = 0.f;

  for (int s = 0; s < 4; ++s) {        // 4 strips of 64 k
    float wv[8][8];                    // W[k = s*64+j*8+i][c], 64 VGPR
#pragma unroll
    for (int i = 0; i < 8; ++i) {
      int k = s * 64 + j * 8 + i;
      float4 w0 = *(const float4*)(W + k * 8);
      float4 w1 = *(const float4*)(W + k * 8 + 4);
      wv[i][0] = w0.x; wv[i][1] = w0.y; wv[i][2] = w0.z; wv[i][3] = w0.w;
      wv[i][4] = w1.x; wv[i][5] = w1.y; wv[i][6] = w1.z; wv[i][7] = w1.w;
    }
#pragma unroll
    for (int rt = 0; rt < 2; ++rt) {
      int lrow = w * 16 + rt * 8 + rr;
      const float* xr = &s_x[lrow * 260 + s * 64 + j * 8];
      float4 x0 = *(const float4*)(xr);
      float4 x1 = *(const float4*)(xr + 4);
      float xv[8] = {x0.x, x0.y, x0.z, x0.w, x1.x, x1.y, x1.z, x1.w};
#pragma unroll
      for (int i = 0; i < 8; ++i)
#pragma unroll
        for (int c = 0; c < 8; ++c)
          acc[rt][c] = fmaf(xv[i], wv[i][c], acc[rt][c]);
    }
  }
  // ---- rotation butterfly over j (xor 1,2,4): lane j ends with column j ----
  int jb1 = j & 1, jb2 = (j >> 1) & 1, jb4 = (j >> 2) & 1;
  float r1[2][4], r2[2][2], r3[2];
#pragma unroll
  for (int rt = 0; rt < 2; ++rt) {
#pragma unroll
    for (int u = 0; u < 4; ++u) {
      float keep = jb1 ? acc[rt][2 * u + 1] : acc[rt][2 * u];
      float send = jb1 ? acc[rt][2 * u] : acc[rt][2 * u + 1];
      r1[rt][u] = keep + __shfl_xor(send, 1, 64);
    }
#pragma unroll
    for (int u = 0; u < 2; ++u) {
      float keep = jb2 ? r1[rt][2 * u + 1] : r1[rt][2 * u];
      float send = jb2 ? r1[rt][2 * u] : r1[rt][2 * u + 1];
      r2[rt][u] = keep + __shfl_xor(send, 2, 64);
    }
    {
      float keep = jb4 ? r2[rt][1] : r2[rt][0];
      float send = jb4 ? r2[rt][0] : r2[rt][1];
      r3[rt] = keep + __shfl_xor(send, 4, 64);
    }
  }
  float bj = b[j];
#pragma unroll
  for (int rt = 0; rt < 2; ++rt) {
    int grow = base_row + w * 16 + rt * 8 + rr;
    h[(size_t)grow * 8 + j] = r3[rt] + bj;
  }
}

// ---------------------------------------------------------------------------
// Phase 1: bucket binning (dense writes, one global atomic per block-bucket).
// ---------------------------------------------------------------------------
__global__ __launch_bounds__(256) void bin_kernel(
    const int* __restrict__ e0, const int* __restrict__ e1,
    const int* __restrict__ e2, const int* __restrict__ e3,
    int* __restrict__ gcur, int* __restrict__ edge_src) {
  __shared__ int s_pack[CHUNK];
  __shared__ unsigned char s_buk[CHUNK];
  __shared__ int s_hist[NBUK], s_base[NBUK], s_cur[NBUK];
  int et = blockIdx.y;
  const int* ei = et == 0 ? e0 : et == 1 ? e1 : et == 2 ? e2 : e3;
  int t = threadIdx.x;
  for (int b = t; b < NBUK; b += 256) { s_hist[b] = 0; s_cur[b] = 0; }
  __syncthreads();
  int base = blockIdx.x * CHUNK;
#pragma unroll
  for (int r = 0; r < CHUNK / 256; ++r) {
    int i = r * 256 + t;
    int e = base + i;
    int bk = 255;
    if (e < EE) {
      int s = ei[e];
      int d = ei[EE + e];
      s_pack[i] = s | ((d & (BUKSZ - 1)) << 17);
      bk = d >> BUKBITS;
      atomicAdd(&s_hist[bk], 1);
    }
    s_buk[i] = (unsigned char)bk;
  }
  __syncthreads();
  for (int b = t; b < NBUK; b += 256)
    s_base[b] = atomicAdd(&gcur[et * NBUK + b], s_hist[b]);
  __syncthreads();
#pragma unroll
  for (int r = 0; r < CHUNK / 256; ++r) {
    int i = r * 256 + t;
    int bk = s_buk[i];
    if (bk != 255) {
      int pos = s_base[bk] + atomicAdd(&s_cur[bk], 1);
      if (pos < CAP)  // statistically impossible overflow guard
        edge_src[(size_t)(et * NBUK + bk) * CAP + pos] = s_pack[i];
    }
  }
}

// ---------------------------------------------------------------------------
// Phase 2: per-bucket CSR (LDS hist + scan + in-place scatter, dense writes).
// ---------------------------------------------------------------------------
__global__ __launch_bounds__(256) void csr_kernel(
    const int* __restrict__ gcur, int* __restrict__ edge_src,
    int* __restrict__ counts, int* __restrict__ rowptr) {
  __shared__ int s_data[CAP];
  __shared__ int s_hist[BUKSZ], s_off[BUKSZ], s_part[256];
  int buk = blockIdx.x, et = blockIdx.y, t = threadIdx.x;
  int bsz = gcur[et * NBUK + buk];
  if (bsz > CAP) bsz = CAP;
  int ebase = (et * NBUK + buk) * CAP;
  for (int j = t; j < BUKSZ; j += 256) s_hist[j] = 0;
  __syncthreads();
  for (int i = t; i < bsz; i += 256) {
    int v = edge_src[ebase + i];
    s_data[i] = v;
    atomicAdd(&s_hist[v >> 17], 1);
  }
  __syncthreads();
  int b2 = t * 2;
  int a0 = s_hist[b2], a1 = s_hist[b2 + 1];
  int tot = a0 + a1;
  s_part[t] = tot;
  __syncthreads();
#pragma unroll
  for (int off = 1; off < 256; off <<= 1) {
    int v = (t >= off) ? s_part[t - off] : 0;
    __syncthreads();
    s_part[t] += v;
    __syncthreads();
  }
  int ex = s_part[t] - tot;
  s_off[b2] = ex;
  s_off[b2 + 1] = ex + a0;
  __syncthreads();
  for (int j = t; j < BUKSZ; j += 256) {
    int node = buk * BUKSZ + j;
    if (node < NN) {
      counts[(size_t)et * NN + node] = s_hist[j];
      rowptr[(size_t)et * NN + node] = ebase + s_off[j];
    }
  }
  __syncthreads();
  for (int i = t; i < bsz; i += 256) {
    int v = s_data[i];
    int pos = atomicAdd(&s_off[v >> 17], 1);
    edge_src[ebase + pos] = v & 0x1FFFF;
  }
}

// ---------------------------------------------------------------------------
// GAT pull: one thread per dst node. alpha_s recomputed in-register; only
// random gather is h_src (3.2MB/XCD via src-type XCD affinity).
// ---------------------------------------------------------------------------
__global__ __launch_bounds__(256) void gat_pull(
    const float* __restrict__ h,
    const int* __restrict__ rowptr, const int* __restrict__ counts,
    const int* __restrict__ edge_src,
    const float* __restrict__ Wsrc_all, const float* __restrict__ Vs,
    const float* __restrict__ Vd,
    const float* __restrict__ bias_all, float* __restrict__ out_et) {
  int b = blockIdx.x;
  int xcd = b & 7;
  int g_ = xcd >> 2;                      // src type this XCD owns
  int sid = (b >> 3) * 4 + (xcd & 3);     // 0..783
  if (sid >= 2 * NODEBLK) return;
  int et = (sid < NODEBLK) ? g_ : g_ + 2; // a:{0,2}  p:{1,3}
  int nb = (sid < NODEBLK) ? sid : sid - NODEBLK;
  int n = nb * 256 + threadIdx.x;
  if (n >= NN) return;
  int st = et & 1;                           // src type: 0=a,1=p
  int dt = (et & 1) ^ (et < 2 ? 1 : 0);      // dst type
  const float* hsrc = h + (size_t)st * NN * 8;
  const float* hdst = h + (size_t)dt * NN * 8;
  const float* Ws = Wsrc_all + et * 512;
  const float* Vse = Vs + et * 64;
  const float* Vde = Vd + et * 64;
  const float* bs = bias_all + et * 64;

  float4 hd0 = *(const float4*)(hdst + (size_t)n * 8);
  float4 hd1 = *(const float4*)(hdst + (size_t)n * 8 + 4);
  float hd[8] = {hd0.x, hd0.y, hd0.z, hd0.w, hd1.x, hd1.y, hd1.z, hd1.w};
  float ad[8];
#pragma unroll
  for (int hh = 0; hh < 8; ++hh) {
    float acc = 0.f;
#pragma unroll
    for (int k = 0; k < 8; ++k) acc = fmaf(hd[k], Vde[k * 8 + hh], acc);
    ad[hh] = acc;
  }
  float g[64];
  float z[8];
#pragma unroll
  for (int i = 0; i < 64; ++i) g[i] = 0.f;
#pragma unroll
  for (int hh = 0; hh < 8; ++hh) z[hh] = 0.f;

  int start = rowptr[(size_t)et * NN + n];
  int deg = counts[(size_t)et * NN + n];
  const int* es = edge_src + start;
  for (int i = 0; i < deg; ++i) {
    int s = es[i];
    float4 a0 = *(const float4*)(hsrc + (size_t)s * 8);
    float4 a1 = *(const float4*)(hsrc + (size_t)s * 8 + 4);
    float hs[8] = {a0.x, a0.y, a0.z, a0.w, a1.x, a1.y, a1.z, a1.w};
#pragma unroll
    for (int hh = 0; hh < 8; ++hh) {
      float e = ad[hh];
#pragma unroll
      for (int k = 0; k < 8; ++k) e = fmaf(hs[k], Vse[k * 8 + hh], e);
      e = e > 0.f ? e : SLOPE * e;
      float w = __expf(e);
      z[hh] += w;
#pragma unroll
      for (int k = 0; k < 8; ++k) g[hh * 8 + k] = fmaf(w, hs[k], g[hh * 8 + k]);
    }
  }

  float* op = out_et + ((size_t)et * NN + n) * 64;
#pragma unroll
  for (int hh = 0; hh < 8; ++hh) {
    float rz = 1.f / (z[hh] + 1e-16f);
    float o[8];
#pragma unroll
    for (int c = 0; c < 8; ++c) {
      float acc = 0.f;
#pragma unroll
      for (int k = 0; k < 8; ++k)
        acc = fmaf(g[hh * 8 + k], Ws[k * 64 + hh * 8 + c], acc);
      o[c] = acc * rz + bs[hh * 8 + c];
    }
    *(float4*)(op + hh * 8) = make_float4(o[0], o[1], o[2], o[3]);
    *(float4*)(op + hh * 8 + 4) = make_float4(o[4], o[5], o[6], o[7]);
  }
}

// ---------------------------------------------------------------------------
// Semantic attention keys: key[m][j] = sum_n tanh(out_et[m][n] @ Wk + bk)[j]
// Lane = output column j; wave = node (row loads wave-uniform).
// ---------------------------------------------------------------------------
__global__ __launch_bounds__(256) void semantic_key(
    const float* __restrict__ out_et, const float* __restrict__ Wk,
    const float* __restrict__ bk, float* __restrict__ key) {
  __shared__ float s_red[256];
  int m = blockIdx.y;
  int lane = threadIdx.x & 63;
  float wcol[64];
#pragma unroll
  for (int k = 0; k < 64; ++k) wcol[k] = Wk[k * 64 + lane];
  float bj = bk[lane];
  float ka = 0.f;
  const float* base = out_et + (size_t)m * NN * 64;
  int gw = blockIdx.x * 4 + (threadIdx.x >> 6);
  for (int n = gw; n < NN; n += SKW) {
    int nu = __builtin_amdgcn_readfirstlane(n);
    const float* row = base + (size_t)nu * 64;
    float a0 = bj, a1 = 0.f, a2 = 0.f, a3 = 0.f;
#pragma unroll
    for (int k4 = 0; k4 < 16; ++k4) {
      float4 r = *(const float4*)(row + k4 * 4);
      a0 = fmaf(r.x, wcol[k4 * 4 + 0], a0);
      a1 = fmaf(r.y, wcol[k4 * 4 + 1], a1);
      a2 = fmaf(r.z, wcol[k4 * 4 + 2], a2);
      a3 = fmaf(r.w, wcol[k4 * 4 + 3], a3);
    }
    float x = (a0 + a1) + (a2 + a3);
    float t = 1.f - 2.f / (__expf(2.f * x) + 1.f);  // tanh
    ka += t;
  }
  s_red[threadIdx.x] = ka;
  __syncthreads();
  if (threadIdx.x < 64) {
    float v = s_red[lane] + s_red[64 + lane] + s_red[128 + lane] +
              s_red[192 + lane];
    atomicAdd(&key[m * 64 + lane], v);
  }
}

// ---------------------------------------------------------------------------
// Scores: softmax over each node-type's pair of edge types.
// ---------------------------------------------------------------------------
__global__ __launch_bounds__(64) void scores_k(
    const float* __restrict__ key, const float* __restrict__ q,
    float* __restrict__ wsc) {
  int l = threadIdx.x;
  float qv = q[l];
  float d[4];
#pragma unroll
  for (int m = 0; m < 4; ++m) {
    float p = qv * key[m * 64 + l];
#pragma unroll
    for (int off = 32; off; off >>= 1) p += __shfl_xor(p, off, 64);
    d[m] = p * (1.0f / NN);  // mean over nodes
  }
  if (l == 0) {
    {
      float mx = fmaxf(d[1], d[2]);
      float e1 = __expf(d[1] - mx), e2 = __expf(d[2] - mx);
      float inv = 1.f / (e1 + e2);
      wsc[1] = e1 * inv;
      wsc[2] = e2 * inv;
    }
    {
      float mx = fmaxf(d[0], d[3]);
      float e0 = __expf(d[0] - mx), e3 = __expf(d[3] - mx);
      float inv = 1.f / (e0 + e3);
      wsc[0] = e0 * inv;
      wsc[3] = e3 * inv;
    }
  }
}

__global__ __launch_bounds__(256) void combine_kernel(
    const float* __restrict__ out_et, const float* __restrict__ wsc,
    float* __restrict__ out) {
  size_t i4 = (size_t)blockIdx.x * 256 + threadIdx.x;  // float4 index over [2][N][16]
  if (i4 >= (size_t)2 * NN * 16) return;
  int type = i4 >= (size_t)NN * 16;
  size_t r4 = type ? i4 - (size_t)NN * 16 : i4;
  int m0 = type ? 0 : 1;
  int m1 = type ? 3 : 2;
  float s0 = wsc[m0], s1 = wsc[m1];
  float4 a = ((const float4*)out_et)[(size_t)m0 * NN * 16 + r4];
  float4 b = ((const float4*)out_et)[(size_t)m1 * NN * 16 + r4];
  float4 o;
  o.x = s0 * a.x + s1 * b.x;
  o.y = s0 * a.y + s1 * b.y;
  o.z = s0 * a.z + s1 * b.z;
  o.w = s0 * a.w + s1 * b.w;
  ((float4*)out)[i4] = o;
}

// ---------------------------------------------------------------------------
extern "C" void kernel_launch(void* const* d_in, const int* in_sizes, int n_in,
                              void* d_out, int out_size, void* d_ws,
                              size_t ws_size, hipStream_t stream) {
  const float* x_a = (const float*)d_in[0];
  const float* x_p = (const float*)d_in[1];
  const int* ei0 = (const int*)d_in[2];   // a->p
  const int* ei1 = (const int*)d_in[3];   // p->a
  const int* ei2 = (const int*)d_in[4];   // a->a
  const int* ei3 = (const int*)d_in[5];   // p->p
  const float* Wfa = (const float*)d_in[6];
  const float* bfa = (const float*)d_in[7];
  const float* Wfp = (const float*)d_in[8];
  const float* bfp = (const float*)d_in[9];
  const float* gWs = (const float*)d_in[10];
  const float* gWd = (const float*)d_in[11];
  const float* gas = (const float*)d_in[12];
  const float* gad = (const float*)d_in[13];
  const float* gb = (const float*)d_in[14];
  const float* Wk = (const float*)d_in[15];
  const float* bk = (const float*)d_in[16];
  const float* q = (const float*)d_in[17];
  float* out = (float*)d_out;
  (void)in_sizes; (void)n_in; (void)out_size; (void)ws_size;

  float* ws = (float*)d_ws;
  float* h = ws;                                     // 2*N*8
  float* out_et = h + (size_t)2 * NN * 8;            // 4*N*64
  float* Vs = out_et + (size_t)4 * NN * 64;          // 256
  float* Vd = Vs + 256;                              // 256
  float* key = Vd + 256;                             // 256
  float* wsc = key + 256;                            // 8 (4 used)
  int* counts = (int*)(wsc + 8);                     // 4*N
  int* rowptr = counts + (size_t)4 * NN;             // 4*N
  int* gcur = rowptr + (size_t)4 * NN;               // 4*NBUK (pad 1024)
  int* edge_src = gcur + 1024;                       // 4*NBUK*CAP ints

  hipMemsetAsync(gcur, 0, 1024 * sizeof(int), stream);
  hipMemsetAsync(key, 0, 256 * sizeof(float), stream);

  prep_V<<<1, 512, 0, stream>>>(gWs, gas, gWd, gad, Vs, Vd);
  fc_kernel<<<FCTILES, 256, 0, stream>>>(x_a, x_p, Wfa, bfa, Wfp, bfp, h);
  bin_kernel<<<dim3(BINBLK, 4), 256, 0, stream>>>(ei0, ei1, ei2, ei3, gcur, edge_src);
  csr_kernel<<<dim3(NBUK, 4), 256, 0, stream>>>(gcur, edge_src, counts, rowptr);
  gat_pull<<<1568, 256, 0, stream>>>(h, rowptr, counts, edge_src,
                                     gWs, Vs, Vd, gb, out_et);
  semantic_key<<<dim3(256, 4), 256, 0, stream>>>(out_et, Wk, bk, key);
  scores_k<<<1, 64, 0, stream>>>(key, q, wsc);
  combine_kernel<<<(2 * NN * 16 + 255) / 256, 256, 0, stream>>>(out_et, wsc, out);
}

// Round 6
// 386.516 us; speedup vs baseline: 3.2567x; 1.1142x over previous
//
#include <hip/hip_runtime.h>
#include <math.h>

#define NN 100000
#define EE 1600000
#define IND 256
#define SLOPE 0.2f

#define BUKBITS 9
#define BUKSZ 512            // nodes per bucket
#define NBUK 196             // ceil(NN/512)
#define CAP 8960             // bucket capacity: mean 8192 + 8*sigma(90)
#define CHUNK 4096           // edges per bin block
#define BINBLK 391           // ceil(EE/CHUNK)
#define NODEBLK 391          // ceil(NN/256)
#define SKW 1024             // semantic_key: waves per m-slice (256 blk x 4)

// ---------------------------------------------------------------------------
// V matrices: alpha = h @ V,  V[et][k][h] = sum_c W[et][k][h*8+c] * a[et][h][c]
// ---------------------------------------------------------------------------
__global__ __launch_bounds__(512) void prep_V(
    const float* __restrict__ Ws, const float* __restrict__ as_,
    const float* __restrict__ Wd, const float* __restrict__ ad_,
    float* __restrict__ Vs, float* __restrict__ Vd) {
  int t = threadIdx.x;             // 0..511
  int half = t >> 8;
  int r = t & 255;
  int et = r >> 6, k = (r >> 3) & 7, hh = r & 7;
  const float* W = half ? Wd : Ws;
  const float* a = half ? ad_ : as_;
  float acc = 0.f;
#pragma unroll
  for (int c = 0; c < 8; ++c)
    acc += W[et * 512 + k * 64 + hh * 8 + c] * a[et * 64 + hh * 8 + c];
  (half ? Vd : Vs)[et * 64 + k * 8 + hh] = acc;
}

// ---------------------------------------------------------------------------
// FC: h[row][0..7] = x[row] @ Wfc + b.  Thread-per-row streaming GEMM (N=8).
// W staged once in 8KB LDS, read as uniform broadcasts (conflict-free).
// Blocks 0..NODEBLK-1 = author rows, NODEBLK..2*NODEBLK-1 = paper rows, so
// the W pointer is block-uniform. Lanes stream their own 1KB row; the 64
// lines/instr are fully consumed across 4 consecutive iterations via L1.
// ---------------------------------------------------------------------------
__global__ __launch_bounds__(256) void fc_kernel(
    const float* __restrict__ xa, const float* __restrict__ xp,
    const float* __restrict__ Wa, const float* __restrict__ ba,
    const float* __restrict__ Wp, const float* __restrict__ bp,
    float* __restrict__ h) {
  __shared__ float sW[IND * 8];    // 8 KB
  __shared__ float sB[8];
  int bid = blockIdx.x;
  int type = bid >= NODEBLK;
  int lrow = (type ? bid - NODEBLK : bid) * 256 + threadIdx.x;
  const float* W = type ? Wp : Wa;
  const float* bb = type ? bp : ba;
  for (int i = threadIdx.x; i < IND * 8; i += 256) sW[i] = W[i];
  if (threadIdx.x < 8) sB[threadIdx.x] = bb[threadIdx.x];
  __syncthreads();
  if (lrow >= NN) return;
  const float* x = (type ? xp : xa) + (size_t)lrow * IND;
  float acc[8];
#pragma unroll
  for (int c = 0; c < 8; ++c) acc[c] = sB[c];
#pragma unroll 4
  for (int k4 = 0; k4 < IND / 4; ++k4) {
    float4 xv = ((const float4*)x)[k4];
    float xk[4] = {xv.x, xv.y, xv.z, xv.w};
#pragma unroll
    for (int kk = 0; kk < 4; ++kk) {
      const float* wr = &sW[(k4 * 4 + kk) * 8];
#pragma unroll
      for (int c = 0; c < 8; ++c) acc[c] = fmaf(xk[kk], wr[c], acc[c]);
    }
  }
  size_t row = (size_t)type * NN + lrow;
  *(float4*)(h + row * 8) = make_float4(acc[0], acc[1], acc[2], acc[3]);
  *(float4*)(h + row * 8 + 4) = make_float4(acc[4], acc[5], acc[6], acc[7]);
}

// ---------------------------------------------------------------------------
// Phase 1: bucket binning (dense writes, one global atomic per block-bucket).
// ---------------------------------------------------------------------------
__global__ __launch_bounds__(256) void bin_kernel(
    const int* __restrict__ e0, const int* __restrict__ e1,
    const int* __restrict__ e2, const int* __restrict__ e3,
    int* __restrict__ gcur, int* __restrict__ edge_src) {
  __shared__ int s_pack[CHUNK];
  __shared__ unsigned char s_buk[CHUNK];
  __shared__ int s_hist[NBUK], s_base[NBUK], s_cur[NBUK];
  int et = blockIdx.y;
  const int* ei = et == 0 ? e0 : et == 1 ? e1 : et == 2 ? e2 : e3;
  int t = threadIdx.x;
  for (int b = t; b < NBUK; b += 256) { s_hist[b] = 0; s_cur[b] = 0; }
  __syncthreads();
  int base = blockIdx.x * CHUNK;
#pragma unroll
  for (int r = 0; r < CHUNK / 256; ++r) {
    int i = r * 256 + t;
    int e = base + i;
    int bk = 255;
    if (e < EE) {
      int s = ei[e];
      int d = ei[EE + e];
      s_pack[i] = s | ((d & (BUKSZ - 1)) << 17);
      bk = d >> BUKBITS;
      atomicAdd(&s_hist[bk], 1);
    }
    s_buk[i] = (unsigned char)bk;
  }
  __syncthreads();
  for (int b = t; b < NBUK; b += 256)
    s_base[b] = atomicAdd(&gcur[et * NBUK + b], s_hist[b]);
  __syncthreads();
#pragma unroll
  for (int r = 0; r < CHUNK / 256; ++r) {
    int i = r * 256 + t;
    int bk = s_buk[i];
    if (bk != 255) {
      int pos = s_base[bk] + atomicAdd(&s_cur[bk], 1);
      if (pos < CAP)  // statistically impossible overflow guard
        edge_src[(size_t)(et * NBUK + bk) * CAP + pos] = s_pack[i];
    }
  }
}

// ---------------------------------------------------------------------------
// Phase 2: per-bucket CSR (LDS hist + scan + in-place scatter, dense writes).
// ---------------------------------------------------------------------------
__global__ __launch_bounds__(256) void csr_kernel(
    const int* __restrict__ gcur, int* __restrict__ edge_src,
    int* __restrict__ counts, int* __restrict__ rowptr) {
  __shared__ int s_data[CAP];
  __shared__ int s_hist[BUKSZ], s_off[BUKSZ], s_part[256];
  int buk = blockIdx.x, et = blockIdx.y, t = threadIdx.x;
  int bsz = gcur[et * NBUK + buk];
  if (bsz > CAP) bsz = CAP;
  int ebase = (et * NBUK + buk) * CAP;
  for (int j = t; j < BUKSZ; j += 256) s_hist[j] = 0;
  __syncthreads();
  for (int i = t; i < bsz; i += 256) {
    int v = edge_src[ebase + i];
    s_data[i] = v;
    atomicAdd(&s_hist[v >> 17], 1);
  }
  __syncthreads();
  int b2 = t * 2;
  int a0 = s_hist[b2], a1 = s_hist[b2 + 1];
  int tot = a0 + a1;
  s_part[t] = tot;
  __syncthreads();
#pragma unroll
  for (int off = 1; off < 256; off <<= 1) {
    int v = (t >= off) ? s_part[t - off] : 0;
    __syncthreads();
    s_part[t] += v;
    __syncthreads();
  }
  int ex = s_part[t] - tot;
  s_off[b2] = ex;
  s_off[b2 + 1] = ex + a0;
  __syncthreads();
  for (int j = t; j < BUKSZ; j += 256) {
    int node = buk * BUKSZ + j;
    if (node < NN) {
      counts[(size_t)et * NN + node] = s_hist[j];
      rowptr[(size_t)et * NN + node] = ebase + s_off[j];
    }
  }
  __syncthreads();
  for (int i = t; i < bsz; i += 256) {
    int v = s_data[i];
    int pos = atomicAdd(&s_off[v >> 17], 1);
    edge_src[ebase + pos] = v & 0x1FFFF;
  }
}

// ---------------------------------------------------------------------------
// GAT pull: one thread per dst node. alpha_s recomputed in-register; only
// random gather is h_src (3.2MB/XCD via src-type XCD affinity).
// ---------------------------------------------------------------------------
__global__ __launch_bounds__(256) void gat_pull(
    const float* __restrict__ h,
    const int* __restrict__ rowptr, const int* __restrict__ counts,
    const int* __restrict__ edge_src,
    const float* __restrict__ Wsrc_all, const float* __restrict__ Vs,
    const float* __restrict__ Vd,
    const float* __restrict__ bias_all, float* __restrict__ out_et) {
  int b = blockIdx.x;
  int xcd = b & 7;
  int g_ = xcd >> 2;                      // src type this XCD owns
  int sid = (b >> 3) * 4 + (xcd & 3);     // 0..783
  if (sid >= 2 * NODEBLK) return;
  int et = (sid < NODEBLK) ? g_ : g_ + 2; // a:{0,2}  p:{1,3}
  int nb = (sid < NODEBLK) ? sid : sid - NODEBLK;
  int n = nb * 256 + threadIdx.x;
  if (n >= NN) return;
  int st = et & 1;                           // src type: 0=a,1=p
  int dt = (et & 1) ^ (et < 2 ? 1 : 0);      // dst type
  const float* hsrc = h + (size_t)st * NN * 8;
  const float* hdst = h + (size_t)dt * NN * 8;
  const float* Ws = Wsrc_all + et * 512;
  const float* Vse = Vs + et * 64;
  const float* Vde = Vd + et * 64;
  const float* bs = bias_all + et * 64;

  float4 hd0 = *(const float4*)(hdst + (size_t)n * 8);
  float4 hd1 = *(const float4*)(hdst + (size_t)n * 8 + 4);
  float hd[8] = {hd0.x, hd0.y, hd0.z, hd0.w, hd1.x, hd1.y, hd1.z, hd1.w};
  float ad[8];
#pragma unroll
  for (int hh = 0; hh < 8; ++hh) {
    float acc = 0.f;
#pragma unroll
    for (int k = 0; k < 8; ++k) acc = fmaf(hd[k], Vde[k * 8 + hh], acc);
    ad[hh] = acc;
  }
  float g[64];
  float z[8];
#pragma unroll
  for (int i = 0; i < 64; ++i) g[i] = 0.f;
#pragma unroll
  for (int hh = 0; hh < 8; ++hh) z[hh] = 0.f;

  int start = rowptr[(size_t)et * NN + n];
  int deg = counts[(size_t)et * NN + n];
  const int* es = edge_src + start;
  for (int i = 0; i < deg; ++i) {
    int s = es[i];
    float4 a0 = *(const float4*)(hsrc + (size_t)s * 8);
    float4 a1 = *(const float4*)(hsrc + (size_t)s * 8 + 4);
    float hs[8] = {a0.x, a0.y, a0.z, a0.w, a1.x, a1.y, a1.z, a1.w};
#pragma unroll
    for (int hh = 0; hh < 8; ++hh) {
      float e = ad[hh];
#pragma unroll
      for (int k = 0; k < 8; ++k) e = fmaf(hs[k], Vse[k * 8 + hh], e);
      e = e > 0.f ? e : SLOPE * e;
      float w = __expf(e);
      z[hh] += w;
#pragma unroll
      for (int k = 0; k < 8; ++k) g[hh * 8 + k] = fmaf(w, hs[k], g[hh * 8 + k]);
    }
  }

  float* op = out_et + ((size_t)et * NN + n) * 64;
#pragma unroll
  for (int hh = 0; hh < 8; ++hh) {
    float rz = 1.f / (z[hh] + 1e-16f);
    float o[8];
#pragma unroll
    for (int c = 0; c < 8; ++c) {
      float acc = 0.f;
#pragma unroll
      for (int k = 0; k < 8; ++k)
        acc = fmaf(g[hh * 8 + k], Ws[k * 64 + hh * 8 + c], acc);
      o[c] = acc * rz + bs[hh * 8 + c];
    }
    *(float4*)(op + hh * 8) = make_float4(o[0], o[1], o[2], o[3]);
    *(float4*)(op + hh * 8 + 4) = make_float4(o[4], o[5], o[6], o[7]);
  }
}

// ---------------------------------------------------------------------------
// Semantic attention keys: key[m][j] = sum_n tanh(out_et[m][n] @ Wk + bk)[j]
// Lane = output column j; wave = node (row loads wave-uniform).
// ---------------------------------------------------------------------------
__global__ __launch_bounds__(256) void semantic_key(
    const float* __restrict__ out_et, const float* __restrict__ Wk,
    const float* __restrict__ bk, float* __restrict__ key) {
  __shared__ float s_red[256];
  int m = blockIdx.y;
  int lane = threadIdx.x & 63;
  float wcol[64];
#pragma unroll
  for (int k = 0; k < 64; ++k) wcol[k] = Wk[k * 64 + lane];
  float bj = bk[lane];
  float ka = 0.f;
  const float* base = out_et + (size_t)m * NN * 64;
  int gw = blockIdx.x * 4 + (threadIdx.x >> 6);
  for (int n = gw; n < NN; n += SKW) {
    int nu = __builtin_amdgcn_readfirstlane(n);
    const float* row = base + (size_t)nu * 64;
    float a0 = bj, a1 = 0.f, a2 = 0.f, a3 = 0.f;
#pragma unroll
    for (int k4 = 0; k4 < 16; ++k4) {
      float4 r = *(const float4*)(row + k4 * 4);
      a0 = fmaf(r.x, wcol[k4 * 4 + 0], a0);
      a1 = fmaf(r.y, wcol[k4 * 4 + 1], a1);
      a2 = fmaf(r.z, wcol[k4 * 4 + 2], a2);
      a3 = fmaf(r.w, wcol[k4 * 4 + 3], a3);
    }
    float x = (a0 + a1) + (a2 + a3);
    float t = 1.f - 2.f / (__expf(2.f * x) + 1.f);  // tanh
    ka += t;
  }
  s_red[threadIdx.x] = ka;
  __syncthreads();
  if (threadIdx.x < 64) {
    float v = s_red[lane] + s_red[64 + lane] + s_red[128 + lane] +
              s_red[192 + lane];
    atomicAdd(&key[m * 64 + lane], v);
  }
}

// ---------------------------------------------------------------------------
// Scores: softmax over each node-type's pair of edge types.
// ---------------------------------------------------------------------------
__global__ __launch_bounds__(64) void scores_k(
    const float* __restrict__ key, const float* __restrict__ q,
    float* __restrict__ wsc) {
  int l = threadIdx.x;
  float qv = q[l];
  float d[4];
#pragma unroll
  for (int m = 0; m < 4; ++m) {
    float p = qv * key[m * 64 + l];
#pragma unroll
    for (int off = 32; off; off >>= 1) p += __shfl_xor(p, off, 64);
    d[m] = p * (1.0f / NN);  // mean over nodes
  }
  if (l == 0) {
    {
      float mx = fmaxf(d[1], d[2]);
      float e1 = __expf(d[1] - mx), e2 = __expf(d[2] - mx);
      float inv = 1.f / (e1 + e2);
      wsc[1] = e1 * inv;
      wsc[2] = e2 * inv;
    }
    {
      float mx = fmaxf(d[0], d[3]);
      float e0 = __expf(d[0] - mx), e3 = __expf(d[3] - mx);
      float inv = 1.f / (e0 + e3);
      wsc[0] = e0 * inv;
      wsc[3] = e3 * inv;
    }
  }
}

__global__ __launch_bounds__(256) void combine_kernel(
    const float* __restrict__ out_et, const float* __restrict__ wsc,
    float* __restrict__ out) {
  size_t i4 = (size_t)blockIdx.x * 256 + threadIdx.x;  // float4 index over [2][N][16]
  if (i4 >= (size_t)2 * NN * 16) return;
  int type = i4 >= (size_t)NN * 16;
  size_t r4 = type ? i4 - (size_t)NN * 16 : i4;
  int m0 = type ? 0 : 1;
  int m1 = type ? 3 : 2;
  float s0 = wsc[m0], s1 = wsc[m1];
  float4 a = ((const float4*)out_et)[(size_t)m0 * NN * 16 + r4];
  float4 b = ((const float4*)out_et)[(size_t)m1 * NN * 16 + r4];
  float4 o;
  o.x = s0 * a.x + s1 * b.x;
  o.y = s0 * a.y + s1 * b.y;
  o.z = s0 * a.z + s1 * b.z;
  o.w = s0 * a.w + s1 * b.w;
  ((float4*)out)[i4] = o;
}

// ---------------------------------------------------------------------------
extern "C" void kernel_launch(void* const* d_in, const int* in_sizes, int n_in,
                              void* d_out, int out_size, void* d_ws,
                              size_t ws_size, hipStream_t stream) {
  const float* x_a = (const float*)d_in[0];
  const float* x_p = (const float*)d_in[1];
  const int* ei0 = (const int*)d_in[2];   // a->p
  const int* ei1 = (const int*)d_in[3];   // p->a
  const int* ei2 = (const int*)d_in[4];   // a->a
  const int* ei3 = (const int*)d_in[5];   // p->p
  const float* Wfa = (const float*)d_in[6];
  const float* bfa = (const float*)d_in[7];
  const float* Wfp = (const float*)d_in[8];
  const float* bfp = (const float*)d_in[9];
  const float* gWs = (const float*)d_in[10];
  const float* gWd = (const float*)d_in[11];
  const float* gas = (const float*)d_in[12];
  const float* gad = (const float*)d_in[13];
  const float* gb = (const float*)d_in[14];
  const float* Wk = (const float*)d_in[15];
  const float* bk = (const float*)d_in[16];
  const float* q = (const float*)d_in[17];
  float* out = (float*)d_out;
  (void)in_sizes; (void)n_in; (void)out_size; (void)ws_size;

  float* ws = (float*)d_ws;
  float* h = ws;                                     // 2*N*8
  float* out_et = h + (size_t)2 * NN * 8;            // 4*N*64
  float* Vs = out_et + (size_t)4 * NN * 64;          // 256
  float* Vd = Vs + 256;                              // 256
  float* key = Vd + 256;                             // 256
  float* wsc = key + 256;                            // 8 (4 used)
  int* counts = (int*)(wsc + 8);                     // 4*N
  int* rowptr = counts + (size_t)4 * NN;             // 4*N
  int* gcur = rowptr + (size_t)4 * NN;               // 4*NBUK (pad 1024)
  int* edge_src = gcur + 1024;                       // 4*NBUK*CAP ints

  hipMemsetAsync(gcur, 0, 1024 * sizeof(int), stream);
  hipMemsetAsync(key, 0, 256 * sizeof(float), stream);

  prep_V<<<1, 512, 0, stream>>>(gWs, gas, gWd, gad, Vs, Vd);
  fc_kernel<<<2 * NODEBLK, 256, 0, stream>>>(x_a, x_p, Wfa, bfa, Wfp, bfp, h);
  bin_kernel<<<dim3(BINBLK, 4), 256, 0, stream>>>(ei0, ei1, ei2, ei3, gcur, edge_src);
  csr_kernel<<<dim3(NBUK, 4), 256, 0, stream>>>(gcur, edge_src, counts, rowptr);
  gat_pull<<<1568, 256, 0, stream>>>(h, rowptr, counts, edge_src,
                                     gWs, Vs, Vd, gb, out_et);
  semantic_key<<<dim3(256, 4), 256, 0, stream>>>(out_et, Wk, bk, key);
  scores_k<<<1, 64, 0, stream>>>(key, q, wsc);
  combine_kernel<<<(2 * NN * 16 + 255) / 256, 256, 0, stream>>>(out_et, wsc, out);
}